// Round 2
// baseline (282.269 us; speedup 1.0000x reference)
//
#include <hip/hip_runtime.h>
#include <hip/hip_bf16.h>

// Problem constants (fixed by the reference)
#define B_DIM   16384
#define IN_DIM  512
#define H_DIM   512
#define K_DIM   1024          // IN + H concatenated
#define N4H     2048          // 4*H
#define BH      (B_DIM * H_DIM)

typedef __attribute__((ext_vector_type(8))) short  short8;   // 8 bf16 = one MFMA operand
typedef __attribute__((ext_vector_type(4))) short  short4v;  // 4 bf16 = 8B write
typedef __attribute__((ext_vector_type(4))) float  f32x4;    // MFMA accumulator

__device__ inline void async_load16(const void* g, void* l) {
    __builtin_amdgcn_global_load_lds(
        (const __attribute__((address_space(1))) void*)g,
        (__attribute__((address_space(3)))       void*)l, 16, 0, 0);
}

__device__ inline short bf16bits(float f) {
    __hip_bfloat16 b = __float2bfloat16(f);
    return *reinterpret_cast<short*>(&b);
}

__device__ inline float sigmoidf_(float v) {
    return 1.0f / (1.0f + __expf(-v));
}
__device__ inline float tanhf_(float v) {
    v = fminf(fmaxf(v, -30.f), 30.f);
    float e = __expf(2.f * v);
    return (e - 1.f) / (e + 1.f);
}

// pack 8 fp32 -> 8 bf16 and store 16B to LDS (same conversion as before: RNE)
__device__ inline void store_bf16x8(void* dst, float4 a, float4 b) {
    short8 r;
    r[0] = bf16bits(a.x); r[1] = bf16bits(a.y);
    r[2] = bf16bits(a.z); r[3] = bf16bits(a.w);
    r[4] = bf16bits(b.x); r[5] = bf16bits(b.y);
    r[6] = bf16bits(b.z); r[7] = bf16bits(b.w);
    *(short8*)dst = r;
}

// ---------------------------------------------------------------------------
// Weight-only prep (validated R1/R2 pattern): Wt[row][k] bf16 with row
// permuted nb*128 + gate*32 + col, plus packed bias. ~12 MB traffic, ~6 us.
// The Axh materialization (96 MB round-trip, ~110+ us) is DELETED — the
// fp32->bf16 conversion of x/h now happens inside the GEMM's A-staging.
// ---------------------------------------------------------------------------
__global__ __launch_bounds__(256) void prep_weights(
    const float* __restrict__ Wx, const float* __restrict__ Wh,
    const float* __restrict__ bx, const float* __restrict__ bh,
    __hip_bfloat16* __restrict__ Wt, float* __restrict__ bias_p) {
    __shared__ __hip_bfloat16 tile[32][33];
    const int bid = blockIdx.x;
    const int bk  = bid & 31;
    const int bn  = bid >> 5;
    const int t   = threadIdx.x;
    const int kb  = bk * 32, nb = bn * 32;
#pragma unroll
    for (int r = 0; r < 4; ++r) {
        int k_loc = r * 8 + (t >> 5);
        int n_loc = t & 31;
        int kg = kb + k_loc;
        float v = (kg < IN_DIM) ? Wx[(size_t)kg * N4H + nb + n_loc]
                                : Wh[(size_t)(kg - IN_DIM) * N4H + nb + n_loc];
        tile[k_loc][n_loc] = __float2bfloat16(v);
    }
    __syncthreads();
    {
        int n_loc = t >> 3;
        int k_loc = (t & 7) * 4;
        int ng = nb + n_loc;
        int g  = ng >> 9;
        int c  = ng & 511;
        int row_out = (c >> 5) * 128 + g * 32 + (c & 31);
        short4v v4;
        v4.x = *reinterpret_cast<short*>(&tile[k_loc + 0][n_loc]);
        v4.y = *reinterpret_cast<short*>(&tile[k_loc + 1][n_loc]);
        v4.z = *reinterpret_cast<short*>(&tile[k_loc + 2][n_loc]);
        v4.w = *reinterpret_cast<short*>(&tile[k_loc + 3][n_loc]);
        *(short4v*)&Wt[(size_t)row_out * K_DIM + kb + k_loc] = v4;
    }
    if (bid < 8) {
        int ng = bid * 256 + t;
        int g  = ng >> 9;
        int c  = ng & 511;
        int ro = (c >> 5) * 128 + g * 32 + (c & 31);
        bias_p[ro] = bx[ng] + bh[ng];
    }
}

// ---------------------------------------------------------------------------
// Fused main kernel (R2's validated 128x128/BK=32 structure, MFMA layout,
// additive slot swizzle, XCD pinning, explicit LDS double-buffer) with A
// now reg-staged straight from fp32 x/h:
//   - after the barrier publishing tile kt: issue 4 global_load_dwordx4 of
//     fp32 x/h for tile kt+1 (T14 issue-early) + the 2 B global_load_lds
//   - MFMA phase on tile kt (covers the HBM latency)
//   - convert+ds_write_b128 the A regs into buf 1-p (T14 write-late)
// LDS layout and fragment-read offsets are IDENTICAL to the validated
// version, so the measured-conflict-free property carries over.
// ---------------------------------------------------------------------------
__global__ __launch_bounds__(256, 3) void lstm_gemm_fused(
    const float* __restrict__ x,  const float* __restrict__ h,
    const float* __restrict__ c_in,
    const __hip_bfloat16* __restrict__ Wt,
    const float* __restrict__ bias_p,
    float* __restrict__ out) {
    __shared__ __hip_bfloat16 lds_a[2][128 * 32];   // 2 x 8KB
    __shared__ __hip_bfloat16 lds_b[2][128 * 32];   // 2 x 8KB

    const int tid   = threadIdx.x;
    const int w     = tid >> 6;
    const int lane  = tid & 63;
    const int col16 = lane & 15;
    const int quad  = lane >> 4;

    // XCD-aware decomposition (round-robin block->XCD assumed: j & 7)
    const int jb    = blockIdx.x;
    const int xcd   = jb & 7;
    const int local = jb >> 3;                   // 0..255 per XCD
    const int bm    = xcd * 16 + (local >> 4);   // 0..127
    const int bn    = local & 15;                // 0..15

    f32x4 acc[2][8];
#pragma unroll
    for (int mi = 0; mi < 2; ++mi)
#pragma unroll
        for (int ni = 0; ni < 8; ++ni)
            acc[mi][ni] = (f32x4){0.f, 0.f, 0.f, 0.f};

    const __hip_bfloat16* Bb = Wt + (size_t)bn * 128 * K_DIM;
    const float* xb = x + (size_t)bm * 128 * IN_DIM;
    const float* hb = h + (size_t)bm * 128 * H_DIM;

    // Staging geometry (R2, measured conflict-free):
    // slot s holds row r = s>>2, k-group q = ((s&3) - ((r>>1)&3)) & 3.
    const int s0 = w * 128 + lane;
    const int s1 = s0 + 64;
    const int r0 = s0 >> 2, r1 = s1 >> 2;
    const int q0 = ((s0 & 3) - ((r0 >> 1) & 3)) & 3;
    const int q1 = ((s1 & 3) - ((r1 >> 1) & 3)) & 3;
    const size_t ga0 = (size_t)r0 * K_DIM + q0 * 8;   // B source (bf16, prepped)
    const size_t ga1 = (size_t)r1 * K_DIM + q1 * 8;
    const size_t ro0 = (size_t)r0 * 512 + q0 * 8;     // A source (fp32 x/h rows)
    const size_t ro1 = (size_t)r1 * 512 + q1 * 8;

    // ds_read byte offsets within a buffer (constant across K loop)
    int aoff[2], boff[8];
#pragma unroll
    for (int mi = 0; mi < 2; ++mi) {
        int r = w * 32 + mi * 16 + col16;
        aoff[mi] = (r * 4 + ((quad + ((r >> 1) & 3)) & 3)) * 16;
    }
#pragma unroll
    for (int ni = 0; ni < 8; ++ni) {
        int r = ni * 16 + col16;
        boff[ni] = (r * 4 + ((quad + ((r >> 1) & 3)) & 3)) * 16;
    }

    // Prologue: stage tile kt=0 into buffer 0 (kb=0 -> A comes from x).
    float4 A00 = *(const float4*)(xb + ro0);
    float4 A01 = *(const float4*)(xb + ro0 + 4);
    float4 A10 = *(const float4*)(xb + ro1);
    float4 A11 = *(const float4*)(xb + ro1 + 4);
    async_load16(Bb + ga0, (void*)(&lds_b[0][w * 1024]));
    async_load16(Bb + ga1, (void*)(&lds_b[0][w * 1024 + 512]));
    store_bf16x8((char*)lds_a[0] + s0 * 16, A00, A01);
    store_bf16x8((char*)lds_a[0] + s1 * 16, A10, A11);

    for (int kt = 0; kt < 32; ++kt) {
        __syncthreads();                 // drains loads/writes(kt), publishes buf p
        const int p = kt & 1;
        if (kt < 31) {                   // T14 issue-early: loads for tile kt+1
            const int kb = (kt + 1) * 32;
            const float* sA = (kb < IN_DIM) ? (xb + kb) : (hb + (kb - IN_DIM));
            A00 = *(const float4*)(sA + ro0);
            A01 = *(const float4*)(sA + ro0 + 4);
            A10 = *(const float4*)(sA + ro1);
            A11 = *(const float4*)(sA + ro1 + 4);
            async_load16(Bb + ga0 + kb, (void*)(&lds_b[1 - p][w * 1024]));
            async_load16(Bb + ga1 + kb, (void*)(&lds_b[1 - p][w * 1024 + 512]));
        }
        const char* lap = (const char*)lds_a[p];
        const char* lbp = (const char*)lds_b[p];

        short8 afr[2], bfr[8];
#pragma unroll
        for (int mi = 0; mi < 2; ++mi)
            afr[mi] = *(const short8*)(lap + aoff[mi]);
#pragma unroll
        for (int ni = 0; ni < 8; ++ni)
            bfr[ni] = *(const short8*)(lbp + boff[ni]);
#pragma unroll
        for (int mi = 0; mi < 2; ++mi)
#pragma unroll
            for (int ni = 0; ni < 8; ++ni)
                acc[mi][ni] = __builtin_amdgcn_mfma_f32_16x16x32_bf16(
                    afr[mi], bfr[ni], acc[mi][ni], 0, 0, 0);

        if (kt < 31) {                   // T14 write-late: convert + publish A(kt+1)
            store_bf16x8((char*)lds_a[1 - p] + s0 * 16, A00, A01);
            store_bf16x8((char*)lds_a[1 - p] + s1 * 16, A10, A11);
        }
    }

    // ---- fused LSTM epilogue (R2, validated) ----
    float bias_v[4][2];
#pragma unroll
    for (int g = 0; g < 4; ++g)
#pragma unroll
        for (int h2 = 0; h2 < 2; ++h2)
            bias_v[g][h2] = bias_p[bn * 128 + g * 32 + h2 * 16 + col16];

#pragma unroll
    for (int mi = 0; mi < 2; ++mi) {
#pragma unroll
        for (int reg = 0; reg < 4; ++reg) {
            const int m_g = bm * 128 + w * 32 + mi * 16 + quad * 4 + reg;
#pragma unroll
            for (int h2 = 0; h2 < 2; ++h2) {
                const int hc_g = bn * 32 + h2 * 16 + col16;
                float gi = acc[mi][0 + h2][reg] + bias_v[0][h2];
                float gf = acc[mi][2 + h2][reg] + bias_v[1][h2];
                float gg = acc[mi][4 + h2][reg] + bias_v[2][h2];
                float go = acc[mi][6 + h2][reg] + bias_v[3][h2];
                float iv = sigmoidf_(gi);
                float fv = sigmoidf_(gf);
                float gv = tanhf_(gg);
                float ov = sigmoidf_(go);
                float co = c_in[(size_t)m_g * H_DIM + hc_g];
                float cn = fv * co + iv * gv;
                float hn = ov * tanhf_(cn);
                out[(size_t)m_g * H_DIM + hc_g]      = hn;   // h_new
                out[BH + (size_t)m_g * H_DIM + hc_g] = cn;   // c_new
            }
        }
    }
}

extern "C" void kernel_launch(void* const* d_in, const int* in_sizes, int n_in,
                              void* d_out, int out_size, void* d_ws, size_t ws_size,
                              hipStream_t stream) {
    const float* x  = (const float*)d_in[0];
    const float* h  = (const float*)d_in[1];
    const float* c  = (const float*)d_in[2];
    const float* Wx = (const float*)d_in[3];
    const float* Wh = (const float*)d_in[4];
    const float* bx = (const float*)d_in[5];
    const float* bh = (const float*)d_in[6];

    const size_t wtBytes = (size_t)N4H * K_DIM * 2;    // 4 MB
    __hip_bfloat16* Wt = (__hip_bfloat16*)d_ws;
    float* bias_p = (float*)((char*)d_ws + wtBytes);

    prep_weights<<<2048, 256, 0, stream>>>(Wx, Wh, bx, bh, Wt, bias_p);
    lstm_gemm_fused<<<2048, 256, 0, stream>>>(x, h, c, Wt, bias_p, (float*)d_out);
}

// Round 4
// 261.318 us; speedup vs baseline: 1.0802x; 1.0802x over previous
//
#include <hip/hip_runtime.h>
#include <hip/hip_bf16.h>

// Problem constants (fixed by the reference)
#define B_DIM   16384
#define IN_DIM  512
#define H_DIM   512
#define K_DIM   1024          // IN + H concatenated
#define N4H     2048          // 4*H
#define BH      (B_DIM * H_DIM)

typedef __attribute__((ext_vector_type(8))) short  short8;   // 8 bf16 = one MFMA operand
typedef __attribute__((ext_vector_type(4))) short  short4v;  // 4 bf16 = 8B write
typedef __attribute__((ext_vector_type(4))) float  f32x4;    // MFMA accumulator

__device__ inline void async_load16(const void* g, void* l) {
    __builtin_amdgcn_global_load_lds(
        (const __attribute__((address_space(1))) void*)g,
        (__attribute__((address_space(3)))       void*)l, 16, 0, 0);
}

__device__ inline short bf16bits(float f) {
    __hip_bfloat16 b = __float2bfloat16(f);
    return *reinterpret_cast<short*>(&b);
}

__device__ inline float sigmoidf_(float v) {
    return 1.0f / (1.0f + __expf(-v));
}
__device__ inline float tanhf_(float v) {
    v = fminf(fmaxf(v, -30.f), 30.f);
    float e = __expf(2.f * v);
    return (e - 1.f) / (e + 1.f);
}

// ---------------------------------------------------------------------------
// Combined prep (validated): Wt gate-permuted bf16 + Axh = bf16(x||h) + bias.
// Measured ~33us total.
// ---------------------------------------------------------------------------
__global__ __launch_bounds__(256) void prep_all(
    const float* __restrict__ Wx, const float* __restrict__ Wh,
    const float* __restrict__ bx, const float* __restrict__ bh,
    const float* __restrict__ x,  const float* __restrict__ h,
    __hip_bfloat16* __restrict__ Wt, __hip_bfloat16* __restrict__ Axh,
    float* __restrict__ bias_p) {
    const int bid = blockIdx.x;
    const int t   = threadIdx.x;

    if (bid < 2048) {
        __shared__ __hip_bfloat16 tile[32][33];
        const int bk = bid & 31;
        const int bn = bid >> 5;
        const int kb = bk * 32, nb = bn * 32;
#pragma unroll
        for (int r = 0; r < 4; ++r) {
            int k_loc = r * 8 + (t >> 5);
            int n_loc = t & 31;
            int kg = kb + k_loc;
            float v = (kg < IN_DIM) ? Wx[(size_t)kg * N4H + nb + n_loc]
                                    : Wh[(size_t)(kg - IN_DIM) * N4H + nb + n_loc];
            tile[k_loc][n_loc] = __float2bfloat16(v);
        }
        __syncthreads();
        {
            int n_loc = t >> 3;
            int k_loc = (t & 7) * 4;
            int ng = nb + n_loc;
            int g  = ng >> 9;
            int c  = ng & 511;
            int row_out = (c >> 5) * 128 + g * 32 + (c & 31);
            short4v v4;
            v4.x = *reinterpret_cast<short*>(&tile[k_loc + 0][n_loc]);
            v4.y = *reinterpret_cast<short*>(&tile[k_loc + 1][n_loc]);
            v4.z = *reinterpret_cast<short*>(&tile[k_loc + 2][n_loc]);
            v4.w = *reinterpret_cast<short*>(&tile[k_loc + 3][n_loc]);
            *(short4v*)&Wt[(size_t)row_out * K_DIM + kb + k_loc] = v4;
        }
        if (bid < 8) {
            int ng = bid * 256 + t;
            int g  = ng >> 9;
            int c  = ng & 511;
            int ro = (c >> 5) * 128 + g * 32 + (c & 31);
            bias_p[ro] = bx[ng] + bh[ng];
        }
    } else {
        const int ab = bid - 2048;              // 0..2047, 8 rows each
        const int kq = t;                       // float4 index within row
        const float* src = (kq < 128) ? (x + kq * 4)
                                      : (h + (size_t)(kq - 128) * 4);
#pragma unroll
        for (int j = 0; j < 8; ++j) {
            int m = ab * 8 + j;
            float4 v = *(const float4*)(src + (size_t)m * 512);
            short4v sv;
            sv.x = bf16bits(v.x);
            sv.y = bf16bits(v.y);
            sv.z = bf16bits(v.z);
            sv.w = bf16bits(v.w);
            *(short4v*)&Axh[(size_t)m * K_DIM + kq * 4] = sv;
        }
    }
}

// ---------------------------------------------------------------------------
// Triple-buffered counted-vmcnt GEMM (256x128 tile, BK=64) + fused epilogue.
//   - 1024 blocks (64 bm x 16 bn), 512 threads = 8 waves (4M x 2N)
//   - wave tile 64 rows x (16 ch x 4 gates); ni == gate -> thread-local epilogue
//   - LDS 3 bufs x (32KB A + 16KB B) = 144KB, 1 block/CU
//   - schedule per K-tile t:  vmcnt(6) [drain own tile-t loads, keep t+1's]
//       -> s_barrier [all waves' tile-t data valid]  -> sched_barrier(0)
//       -> STAGE tile t+2 [buf held tile t-1; its readers finished pre-barrier]
//       -> ds_read + 32 MFMA (setprio 1)
//     Drain-BEFORE-barrier makes the counted wait cross-wave safe (m201/T3
//     invariant); loads ride 2 compute phases ahead, never drained to 0.
//   - XOR swizzle byte ^= ((row&7)<<4); staged via pre-swizzled global source
//     with linear DMA dest (m173): physical slot pg holds logical pg^(r&7).
// ---------------------------------------------------------------------------
__global__ __launch_bounds__(512, 2) void lstm_gemm8t(
    const float* __restrict__ c_in,
    const __hip_bfloat16* __restrict__ Axh,
    const __hip_bfloat16* __restrict__ Wt,
    const float* __restrict__ bias_p,
    float* __restrict__ out) {
    __shared__ __align__(16) __hip_bfloat16 lds_a[3][16384];  // 3 x 32KB
    __shared__ __align__(16) __hip_bfloat16 lds_b[3][8192];   // 3 x 16KB

    const int tid   = threadIdx.x;
    const int w     = tid >> 6;          // wave 0..7
    const int lane  = tid & 63;
    const int col16 = lane & 15;
    const int quad  = lane >> 4;
    const int wm    = w >> 1;            // 0..3  (M quarter: 64 rows)
    const int wnn   = w & 1;             // 0..1  (channel half: 16 ch)

    // XCD-aware decomposition: 1024 blocks = 8 XCD x 128; per XCD 8 bm x 16 bn
    const int jb    = blockIdx.x;
    const int xcd   = jb & 7;
    const int local = jb >> 3;                   // 0..127
    const int bm    = xcd * 8 + (local >> 4);    // 0..63
    const int bn    = local & 15;                // 0..15

    f32x4 acc[4][4];
#pragma unroll
    for (int mi = 0; mi < 4; ++mi)
#pragma unroll
        for (int ni = 0; ni < 4; ++ni)
            acc[mi][ni] = (f32x4){0.f, 0.f, 0.f, 0.f};

    const __hip_bfloat16* Ab = Axh + (size_t)bm * 256 * K_DIM;
    const __hip_bfloat16* Bb = Wt  + (size_t)bn * 128 * K_DIM;

    // ---- staging geometry (pre-swizzled global source, linear LDS dest) ----
    // granule g = j*512 + w*64 + lane (16B) -> row j*64 + w*8 + (lane>>3),
    // physical slot pg = lane&7 holds logical k-granule lg = pg ^ (row&7).
    const int rsub = lane >> 3;
    const int lg   = (lane & 7) ^ rsub;

    // 6 loads per thread per K-tile: A rows {0,64,128,192}+w*8+rsub,
    // B rows {0,64}+w*8+rsub.  FIFO order A0..A3,B0,B1 (vmcnt counts this).
    auto STAGE = [&](int buf, int kt) {
        char* ba = (char*)lds_a[buf] + w * 1024;
        char* bb = (char*)lds_b[buf] + w * 1024;
        const __hip_bfloat16* As = Ab + (size_t)(w * 8 + rsub) * K_DIM + kt * 64 + lg * 8;
        const __hip_bfloat16* Bs = Bb + (size_t)(w * 8 + rsub) * K_DIM + kt * 64 + lg * 8;
        async_load16(As,                      ba);
        async_load16(As +  64 * K_DIM,        ba + 8192);
        async_load16(As + 128 * K_DIM,        ba + 16384);
        async_load16(As + 192 * K_DIM,        ba + 24576);
        async_load16(Bs,                      bb);
        async_load16(Bs +  64 * K_DIM,        bb + 8192);
    };

    // ---- fragment-read byte offsets (swizzled) ----
    // afr row = wm*64 + mi*16 + col16 (A, 0..255)
    // bfr row = ni*32 + wnn*16 + col16 (B, 0..127; ni == gate)
    // byte = row*128 + ((ks*64 + quad*16) ^ ((row&7)<<4)); row&7 == col16&7.
    int arow[4], brow[4], kx[2];
#pragma unroll
    for (int mi = 0; mi < 4; ++mi)
        arow[mi] = (wm * 64 + mi * 16 + col16) * 128;
#pragma unroll
    for (int ni = 0; ni < 4; ++ni)
        brow[ni] = (ni * 32 + wnn * 16 + col16) * 128;
#pragma unroll
    for (int ks = 0; ks < 2; ++ks)
        kx[ks] = (ks * 64 + quad * 16) ^ ((col16 & 7) << 4);

    // ---- prologue: tiles 0 and 1 in flight (12 loads) ----
    STAGE(0, 0);
    STAGE(1, 1);

    int cur = 0;
    for (int t = 0; t < 16; ++t) {
        // drain own tile-t loads (oldest 6), keep tile-t+1's 6 in flight
        if (t < 15) asm volatile("s_waitcnt vmcnt(6)" ::: "memory");
        else        asm volatile("s_waitcnt vmcnt(0)" ::: "memory");
        __builtin_amdgcn_s_barrier();           // all waves' tile-t data valid
        __builtin_amdgcn_sched_barrier(0);      // pin: nothing moves across

        if (t < 14) {
            const int nxt = (cur >= 1) ? cur - 1 : 2;   // (t+2)%3
            STAGE(nxt, t + 2);
        }

        const char* la = (const char*)lds_a[cur];
        const char* lb = (const char*)lds_b[cur];

#pragma unroll
        for (int ks = 0; ks < 2; ++ks) {
            short8 afr[4], bfr[4];
#pragma unroll
            for (int mi = 0; mi < 4; ++mi)
                afr[mi] = *(const short8*)(la + arow[mi] + kx[ks]);
#pragma unroll
            for (int ni = 0; ni < 4; ++ni)
                bfr[ni] = *(const short8*)(lb + brow[ni] + kx[ks]);

            __builtin_amdgcn_s_setprio(1);
#pragma unroll
            for (int mi = 0; mi < 4; ++mi)
#pragma unroll
                for (int ni = 0; ni < 4; ++ni)
                    acc[mi][ni] = __builtin_amdgcn_mfma_f32_16x16x32_bf16(
                        afr[mi], bfr[ni], acc[mi][ni], 0, 0, 0);
            __builtin_amdgcn_s_setprio(0);
        }

        cur = (cur == 2) ? 0 : cur + 1;
    }

    // ---- fused LSTM epilogue (thread-local: ni == gate) ----
    float bias_v[4];
#pragma unroll
    for (int g = 0; g < 4; ++g)
        bias_v[g] = bias_p[bn * 128 + g * 32 + wnn * 16 + col16];

    const int hc_g = bn * 32 + wnn * 16 + col16;

#pragma unroll
    for (int mi = 0; mi < 4; ++mi) {
#pragma unroll
        for (int reg = 0; reg < 4; ++reg) {
            const int m_g = bm * 256 + wm * 64 + mi * 16 + quad * 4 + reg;
            float gi = acc[mi][0][reg] + bias_v[0];
            float gf = acc[mi][1][reg] + bias_v[1];
            float gg = acc[mi][2][reg] + bias_v[2];
            float go = acc[mi][3][reg] + bias_v[3];
            float iv = sigmoidf_(gi);
            float fv = sigmoidf_(gf);
            float gv = tanhf_(gg);
            float ov = sigmoidf_(go);
            float co = c_in[(size_t)m_g * H_DIM + hc_g];
            float cn = fv * co + iv * gv;
            float hn = ov * tanhf_(cn);
            out[(size_t)m_g * H_DIM + hc_g]      = hn;   // h_new
            out[BH + (size_t)m_g * H_DIM + hc_g] = cn;   // c_new
        }
    }
}

// ---------------------------------------------------------------------------
// Fallback path (validated R1 kernels) in case ws_size < 36 MB.
// ---------------------------------------------------------------------------
__global__ __launch_bounds__(256) void prep_weights_fb(
    const float* __restrict__ Wx, const float* __restrict__ Wh,
    const float* __restrict__ bx, const float* __restrict__ bh,
    __hip_bfloat16* __restrict__ Wt, float* __restrict__ bias_p) {
    __shared__ __hip_bfloat16 tile[32][33];
    const int bid = blockIdx.x;
    const int bk  = bid & 31;
    const int bn  = bid >> 5;
    const int t   = threadIdx.x;
    const int kb  = bk * 32, nb = bn * 32;
#pragma unroll
    for (int r = 0; r < 4; ++r) {
        int k_loc = r * 8 + (t >> 5);
        int n_loc = t & 31;
        int kg = kb + k_loc;
        float v = (kg < IN_DIM) ? Wx[(size_t)kg * N4H + nb + n_loc]
                                : Wh[(size_t)(kg - IN_DIM) * N4H + nb + n_loc];
        tile[k_loc][n_loc] = __float2bfloat16(v);
    }
    __syncthreads();
    {
        int n_loc = t >> 3;
        int k_loc = (t & 7) * 4;
        int ng = nb + n_loc;
        int g  = ng >> 9;
        int c  = ng & 511;
        int row_out = (c >> 5) * 128 + g * 32 + (c & 31);
        short4v v4;
        v4.x = *reinterpret_cast<short*>(&tile[k_loc + 0][n_loc]);
        v4.y = *reinterpret_cast<short*>(&tile[k_loc + 1][n_loc]);
        v4.z = *reinterpret_cast<short*>(&tile[k_loc + 2][n_loc]);
        v4.w = *reinterpret_cast<short*>(&tile[k_loc + 3][n_loc]);
        *(short4v*)&Wt[(size_t)row_out * K_DIM + kb + k_loc] = v4;
    }
    if (bid < 8) {
        int ng = bid * 256 + t;
        int g  = ng >> 9;
        int c  = ng & 511;
        int ro = (c >> 5) * 128 + g * 32 + (c & 31);
        bias_p[ro] = bx[ng] + bh[ng];
    }
}

__global__ __launch_bounds__(256, 3) void lstm_gemm_fb(
    const float* __restrict__ x, const float* __restrict__ h,
    const float* __restrict__ c_in,
    const __hip_bfloat16* __restrict__ Wt, const float* __restrict__ bias_p,
    float* __restrict__ out) {
    __shared__ __hip_bfloat16 lds_a[128 * 32];
    __shared__ __hip_bfloat16 lds_b[128 * 32];
    const int tid   = threadIdx.x;
    const int bn    = blockIdx.x & 15;
    const int bm    = blockIdx.x >> 4;
    const int w     = tid >> 6;
    const int lane  = tid & 63;
    const int col16 = lane & 15;
    const int quad  = lane >> 4;
    f32x4 acc[2][8];
#pragma unroll
    for (int mi = 0; mi < 2; ++mi)
#pragma unroll
        for (int ni = 0; ni < 8; ++ni)
            acc[mi][ni] = (f32x4){0.f, 0.f, 0.f, 0.f};
    const __hip_bfloat16* wt_base = Wt + (size_t)(bn * 128) * K_DIM;
    const int chunk0 = w * 2;
    const int e0     = chunk0 * 512 + lane * 8;
    const int bn_loc0 = e0 >> 5, bk_off0 = e0 & 31;
    const int e1     = (chunk0 + 1) * 512 + lane * 8;
    const int bn_loc1 = e1 >> 5, bk_off1 = e1 & 31;
    for (int kt = 0; kt < 32; ++kt) {
        const int kb = kt * 32;
        const float* aptr;
        int koff;
        if (kb < IN_DIM) { aptr = x; koff = kb; }
        else             { aptr = h; koff = kb - IN_DIM; }
        async_load16(wt_base + (size_t)bn_loc0 * K_DIM + kb + bk_off0,
                     (void*)(lds_b + chunk0 * 512));
        async_load16(wt_base + (size_t)bn_loc1 * K_DIM + kb + bk_off1,
                     (void*)(lds_b + (chunk0 + 1) * 512));
        float4 av[4];
#pragma unroll
        for (int j = 0; j < 4; ++j) {
            int cch = j * 256 + tid;
            int row = cch >> 3;
            int kq  = (cch & 7) * 4;
            av[j] = *(const float4*)(aptr + (size_t)(bm * 128 + row) * IN_DIM
                                     + koff + kq);
        }
#pragma unroll
        for (int j = 0; j < 4; ++j) {
            int cch = j * 256 + tid;
            int row = cch >> 3;
            int kq  = (cch & 7) * 4;
            short4v sv;
            sv.x = bf16bits(av[j].x);
            sv.y = bf16bits(av[j].y);
            sv.z = bf16bits(av[j].z);
            sv.w = bf16bits(av[j].w);
            *(short4v*)&lds_a[row * 32 + kq] = sv;
        }
        __syncthreads();
        short8 afr[2], bfr[8];
#pragma unroll
        for (int mi = 0; mi < 2; ++mi)
            afr[mi] = *(const short8*)&lds_a[(w * 32 + mi * 16 + col16) * 32 + quad * 8];
#pragma unroll
        for (int ni = 0; ni < 8; ++ni)
            bfr[ni] = *(const short8*)&lds_b[(ni * 16 + col16) * 32 + quad * 8];
#pragma unroll
        for (int mi = 0; mi < 2; ++mi)
#pragma unroll
            for (int ni = 0; ni < 8; ++ni)
                acc[mi][ni] = __builtin_amdgcn_mfma_f32_16x16x32_bf16(
                    afr[mi], bfr[ni], acc[mi][ni], 0, 0, 0);
        __syncthreads();
    }
    float bias_v[4][2];
#pragma unroll
    for (int g = 0; g < 4; ++g)
#pragma unroll
        for (int h2 = 0; h2 < 2; ++h2)
            bias_v[g][h2] = bias_p[bn * 128 + g * 32 + h2 * 16 + col16];
#pragma unroll
    for (int mi = 0; mi < 2; ++mi) {
#pragma unroll
        for (int reg = 0; reg < 4; ++reg) {
            const int m_g = bm * 128 + w * 32 + mi * 16 + quad * 4 + reg;
#pragma unroll
            for (int h2 = 0; h2 < 2; ++h2) {
                const int hc_g = bn * 32 + h2 * 16 + col16;
                float gi = acc[mi][0 + h2][reg] + bias_v[0][h2];
                float gf = acc[mi][2 + h2][reg] + bias_v[1][h2];
                float gg = acc[mi][4 + h2][reg] + bias_v[2][h2];
                float go = acc[mi][6 + h2][reg] + bias_v[3][h2];
                float iv = sigmoidf_(gi);
                float fv = sigmoidf_(gf);
                float gv = tanhf_(gg);
                float ov = sigmoidf_(go);
                float co = c_in[(size_t)m_g * H_DIM + hc_g];
                float cn = fv * co + iv * gv;
                float hn = ov * tanhf_(cn);
                out[(size_t)m_g * H_DIM + hc_g]      = hn;
                out[BH + (size_t)m_g * H_DIM + hc_g] = cn;
            }
        }
    }
}

extern "C" void kernel_launch(void* const* d_in, const int* in_sizes, int n_in,
                              void* d_out, int out_size, void* d_ws, size_t ws_size,
                              hipStream_t stream) {
    const float* x  = (const float*)d_in[0];
    const float* h  = (const float*)d_in[1];
    const float* c  = (const float*)d_in[2];
    const float* Wx = (const float*)d_in[3];
    const float* Wh = (const float*)d_in[4];
    const float* bx = (const float*)d_in[5];
    const float* bh = (const float*)d_in[6];

    const size_t wtBytes  = (size_t)N4H * K_DIM * 2;    // 4 MB
    const size_t axhBytes = (size_t)B_DIM * K_DIM * 2;  // 32 MB
    const size_t need     = wtBytes + axhBytes + (size_t)N4H * 4;

    if (ws_size >= need) {
        __hip_bfloat16* Wt  = (__hip_bfloat16*)d_ws;
        __hip_bfloat16* Axh = (__hip_bfloat16*)((char*)d_ws + wtBytes);
        float* bias_p = (float*)((char*)d_ws + wtBytes + axhBytes);
        prep_all<<<4096, 256, 0, stream>>>(Wx, Wh, bx, bh, x, h, Wt, Axh, bias_p);
        lstm_gemm8t<<<1024, 512, 0, stream>>>(c, Axh, Wt, bias_p, (float*)d_out);
    } else {
        __hip_bfloat16* Wt = (__hip_bfloat16*)d_ws;
        float* bias_p = (float*)((char*)d_ws + wtBytes);
        prep_weights_fb<<<2048, 256, 0, stream>>>(Wx, Wh, bx, bh, Wt, bias_p);
        lstm_gemm_fb<<<2048, 256, 0, stream>>>(x, h, c, Wt, bias_p, (float*)d_out);
    }
}

// Round 7
// 242.964 us; speedup vs baseline: 1.1618x; 1.0755x over previous
//
#include <hip/hip_runtime.h>
#include <hip/hip_bf16.h>

// Problem constants (fixed by the reference)
#define B_DIM   16384
#define IN_DIM  512
#define H_DIM   512
#define K_DIM   1024          // IN + H concatenated
#define N4H     2048          // 4*H
#define BH      (B_DIM * H_DIM)

typedef __attribute__((ext_vector_type(8))) short  short8;   // 8 bf16 = one MFMA operand
typedef __attribute__((ext_vector_type(4))) short  short4v;  // 4 bf16 = 8B write
typedef __attribute__((ext_vector_type(4))) float  f32x4;    // MFMA accumulator

__device__ inline void async_load16(const void* g, void* l) {
    __builtin_amdgcn_global_load_lds(
        (const __attribute__((address_space(1))) void*)g,
        (__attribute__((address_space(3)))       void*)l, 16, 0, 0);
}

__device__ inline short bf16bits(float f) {
    __hip_bfloat16 b = __float2bfloat16(f);
    return *reinterpret_cast<short*>(&b);
}

__device__ inline float sigmoidf_(float v) {
    return 1.0f / (1.0f + __expf(-v));
}
__device__ inline float tanhf_(float v) {
    v = fminf(fmaxf(v, -30.f), 30.f);
    float e = __expf(2.f * v);
    return (e - 1.f) / (e + 1.f);
}

// ---------------------------------------------------------------------------
// Combined prep (validated): Wt gate-permuted bf16 + Axh = bf16(x||h) + bias.
// Measured ~33us total.
// ---------------------------------------------------------------------------
__global__ __launch_bounds__(256) void prep_all(
    const float* __restrict__ Wx, const float* __restrict__ Wh,
    const float* __restrict__ bx, const float* __restrict__ bh,
    const float* __restrict__ x,  const float* __restrict__ h,
    __hip_bfloat16* __restrict__ Wt, __hip_bfloat16* __restrict__ Axh,
    float* __restrict__ bias_p) {
    const int bid = blockIdx.x;
    const int t   = threadIdx.x;

    if (bid < 2048) {
        __shared__ __hip_bfloat16 tile[32][33];
        const int bk = bid & 31;
        const int bn = bid >> 5;
        const int kb = bk * 32, nb = bn * 32;
#pragma unroll
        for (int r = 0; r < 4; ++r) {
            int k_loc = r * 8 + (t >> 5);
            int n_loc = t & 31;
            int kg = kb + k_loc;
            float v = (kg < IN_DIM) ? Wx[(size_t)kg * N4H + nb + n_loc]
                                    : Wh[(size_t)(kg - IN_DIM) * N4H + nb + n_loc];
            tile[k_loc][n_loc] = __float2bfloat16(v);
        }
        __syncthreads();
        {
            int n_loc = t >> 3;
            int k_loc = (t & 7) * 4;
            int ng = nb + n_loc;
            int g  = ng >> 9;
            int c  = ng & 511;
            int row_out = (c >> 5) * 128 + g * 32 + (c & 31);
            short4v v4;
            v4.x = *reinterpret_cast<short*>(&tile[k_loc + 0][n_loc]);
            v4.y = *reinterpret_cast<short*>(&tile[k_loc + 1][n_loc]);
            v4.z = *reinterpret_cast<short*>(&tile[k_loc + 2][n_loc]);
            v4.w = *reinterpret_cast<short*>(&tile[k_loc + 3][n_loc]);
            *(short4v*)&Wt[(size_t)row_out * K_DIM + kb + k_loc] = v4;
        }
        if (bid < 8) {
            int ng = bid * 256 + t;
            int g  = ng >> 9;
            int c  = ng & 511;
            int ro = (c >> 5) * 128 + g * 32 + (c & 31);
            bias_p[ro] = bx[ng] + bh[ng];
        }
    } else {
        const int ab = bid - 2048;              // 0..2047, 8 rows each
        const int kq = t;                       // float4 index within row
        const float* src = (kq < 128) ? (x + kq * 4)
                                      : (h + (size_t)(kq - 128) * 4);
#pragma unroll
        for (int j = 0; j < 8; ++j) {
            int m = ab * 8 + j;
            float4 v = *(const float4*)(src + (size_t)m * 512);
            short4v sv;
            sv.x = bf16bits(v.x);
            sv.y = bf16bits(v.y);
            sv.z = bf16bits(v.z);
            sv.w = bf16bits(v.w);
            *(short4v*)&Axh[(size_t)m * K_DIM + kq * 4] = sv;
        }
    }
}

// ---------------------------------------------------------------------------
// 4-phase counted-vmcnt 256x256 GEMM (T2+T3+T4+T5) + fused LSTM epilogue.
//   - 512 blocks (64 bm x 8 bn), 512 threads = 8 waves (2M x 4N)
//   - wave tile 128x64; acc[8][4]; ni == gate -> thread-local epilogue
//   - BK=64, 16 K-tiles; LDS [dbuf][khalf][256 rows][32 k] per array = 128KB
//   - staging granule = (array, k-half) = 16KB contiguous (DMA-linear),
//     one granule staged per phase: P0:Akh0  P1:Bkh0  P2:Akh1  P3:Bkh1
//   - reads split by k-half: P0/P1 read kh0, P2/P3 read kh1
//   - counted waits (never 0 mid-loop; drain-BEFORE-barrier => x-wave safe):
//       boundary: vmcnt(4)  drains kh0(t)  [issued 3-4 phases ago], keeps kh1(t)
//       end P1:   vmcnt(4)  drains kh1(t)  [issued 2-3 phases ago], keeps kh0(t+1)
//   - bank swizzle: r0-validated additive rotation slot=(quad+((row>>1)&3))&3
//     on 64B rows, inverse-applied on per-lane GLOBAL source (m173 pattern)
//   - per phase: {ds_read || stage} -> SGB -> barrier -> lgkmcnt(0) -> SGB ->
//     setprio(1) 16xMFMA setprio(0) -> SGB -> [vmcnt @P1] -> barrier
// ---------------------------------------------------------------------------
__global__ __launch_bounds__(512, 2) void lstm_gemm256(
    const float* __restrict__ c_in,
    const __hip_bfloat16* __restrict__ Axh,
    const __hip_bfloat16* __restrict__ Wt,
    const float* __restrict__ bias_p,
    float* __restrict__ out) {
    __shared__ __align__(16) __hip_bfloat16 lds_a[2][16384];  // [dbuf][kh*8192+...]
    __shared__ __align__(16) __hip_bfloat16 lds_b[2][16384];

    const int tid   = threadIdx.x;
    const int w     = tid >> 6;          // wave 0..7
    const int lane  = tid & 63;
    const int col16 = lane & 15;
    const int quad  = lane >> 4;
    const int wm    = w >> 2;            // 0..1  (M half: 128 rows)
    const int wn    = w & 3;             // 0..3  (N quarter: 16ch x 4 gates)

    // XCD-aware decomposition: 512 blocks = 8 XCD x 64; per XCD 8 bm x 8 bn
    const int jb    = blockIdx.x;
    const int xcd   = jb & 7;
    const int local = jb >> 3;                   // 0..63
    const int bm    = xcd * 8 + (local >> 3);    // 0..63  (256 A rows each)
    const int bn    = local & 7;                 // 0..7   (256 Wt rows each)

    f32x4 acc[8][4];
#pragma unroll
    for (int mi = 0; mi < 8; ++mi)
#pragma unroll
        for (int ni = 0; ni < 4; ++ni)
            acc[mi][ni] = (f32x4){0.f, 0.f, 0.f, 0.f};

    const __hip_bfloat16* Ab = Axh + (size_t)bm * 256 * K_DIM;
    const __hip_bfloat16* Bb = Wt  + (size_t)bn * 256 * K_DIM;

    // ---- staging geometry ----
    // granule g = j*512 + tid (16B) -> row = j*128 + (tid>>2), phys slot
    // pg = tid&3.  Slot pg at row r holds logical k-octet lq = (pg-(r>>1))&3;
    // (r>>1)&3 == (tid>>3)&3 for both j.  Source k = kt*64 + kh*32 + lq*8.
    const int lq = ((tid & 3) - ((tid >> 3) & 3)) & 3;

#define STAGE(LDSBUF, GBASE, KH, KT)  do {                                     \
    const __hip_bfloat16* _s = (GBASE) + (size_t)(tid >> 2) * K_DIM            \
                               + (KT) * 64 + (KH) * 32 + lq * 8;               \
    char* _d = (char*)(LDSBUF) + (KH) * 16384 + w * 1024;                      \
    async_load16(_s,                       _d);                                \
    async_load16(_s + (size_t)128 * K_DIM, _d + 8192);                         \
  } while (0)

    // ---- fragment-read byte offsets (r0-validated additive-rotation) ----
    // afr row = wm*128 + mi*16 + col16; bfr row = (wn>>1)*128 + ni*32 +
    // (wn&1)*16 + col16 (ni == gate).  Within kh block (16KB):
    // byte = row*64 + ((quad + ((row>>1)&3))&3)*16 ;  kh adds 16384.
    int aoff[8], boff[4];
#pragma unroll
    for (int mi = 0; mi < 8; ++mi) {
        int r = wm * 128 + mi * 16 + col16;
        aoff[mi] = r * 64 + ((quad + ((r >> 1) & 3)) & 3) * 16;
    }
#pragma unroll
    for (int ni = 0; ni < 4; ++ni) {
        int r = (wn >> 1) * 128 + ni * 32 + (wn & 1) * 16 + col16;
        boff[ni] = r * 64 + ((quad + ((r >> 1) & 3)) & 3) * 16;
    }

    // ---- prologue: stage tile 0 (FIFO: Akh0, Bkh0, Akh1, Bkh1) ----
    STAGE(lds_a[0], Ab, 0, 0);
    STAGE(lds_b[0], Bb, 0, 0);
    STAGE(lds_a[0], Ab, 1, 0);
    STAGE(lds_b[0], Bb, 1, 0);

    short8 afrA[4], afrB[4], bfr[4];

#define PHASE_MID()                                                            \
    __builtin_amdgcn_sched_barrier(0);                                         \
    __builtin_amdgcn_s_barrier();                                              \
    asm volatile("s_waitcnt lgkmcnt(0)" ::: "memory");                         \
    __builtin_amdgcn_sched_barrier(0);

    for (int t = 0; t < 16; ++t) {
        const int cur = t & 1;
        const char* la = (const char*)lds_a[cur];
        const char* lb = (const char*)lds_b[cur];
        __hip_bfloat16* nxa = lds_a[cur ^ 1];
        __hip_bfloat16* nxb = lds_b[cur ^ 1];
        const bool pre = (t < 15);

        // ---- boundary: drain kh0(t) (oldest 4 loads), keep kh1(t) flying ----
        asm volatile("s_waitcnt vmcnt(4)" ::: "memory");
        __builtin_amdgcn_s_barrier();

        // ---- P0: reads A-kh0 (mi 0..3) + B-kh0 ; stage A-kh0(t+1) ----
#pragma unroll
        for (int q = 0; q < 4; ++q) afrA[q] = *(const short8*)(la + aoff[q]);
#pragma unroll
        for (int n = 0; n < 4; ++n) bfr[n] = *(const short8*)(lb + boff[n]);
        if (pre) STAGE(nxa, Ab, 0, t + 1);
        PHASE_MID();
        __builtin_amdgcn_s_setprio(1);
#pragma unroll
        for (int q = 0; q < 4; ++q)
#pragma unroll
            for (int n = 0; n < 4; ++n)
                acc[q][n] = __builtin_amdgcn_mfma_f32_16x16x32_bf16(
                    afrA[q], bfr[n], acc[q][n], 0, 0, 0);
        __builtin_amdgcn_s_setprio(0);
        __builtin_amdgcn_sched_barrier(0);
        __builtin_amdgcn_s_barrier();

        // ---- P1: reads A-kh0 (mi 4..7), bfr reused ; stage B-kh0(t+1) ----
#pragma unroll
        for (int q = 0; q < 4; ++q) afrB[q] = *(const short8*)(la + aoff[q + 4]);
        if (pre) STAGE(nxb, Bb, 0, t + 1);
        PHASE_MID();
        __builtin_amdgcn_s_setprio(1);
#pragma unroll
        for (int q = 0; q < 4; ++q)
#pragma unroll
            for (int n = 0; n < 4; ++n)
                acc[q + 4][n] = __builtin_amdgcn_mfma_f32_16x16x32_bf16(
                    afrB[q], bfr[n], acc[q + 4][n], 0, 0, 0);
        __builtin_amdgcn_s_setprio(0);
        __builtin_amdgcn_sched_barrier(0);
        // drain kh1(t) (needed by P2/P3), keep kh0(t+1) flying
        if (pre) asm volatile("s_waitcnt vmcnt(4)" ::: "memory");
        else     asm volatile("s_waitcnt vmcnt(0)" ::: "memory");
        __builtin_amdgcn_s_barrier();

        // ---- P2: reads A-kh1 (mi 0..3) + B-kh1 ; stage A-kh1(t+1) ----
#pragma unroll
        for (int q = 0; q < 4; ++q) afrA[q] = *(const short8*)(la + 16384 + aoff[q]);
#pragma unroll
        for (int n = 0; n < 4; ++n) bfr[n] = *(const short8*)(lb + 16384 + boff[n]);
        if (pre) STAGE(nxa, Ab, 1, t + 1);
        PHASE_MID();
        __builtin_amdgcn_s_setprio(1);
#pragma unroll
        for (int q = 0; q < 4; ++q)
#pragma unroll
            for (int n = 0; n < 4; ++n)
                acc[q][n] = __builtin_amdgcn_mfma_f32_16x16x32_bf16(
                    afrA[q], bfr[n], acc[q][n], 0, 0, 0);
        __builtin_amdgcn_s_setprio(0);
        __builtin_amdgcn_sched_barrier(0);
        __builtin_amdgcn_s_barrier();

        // ---- P3: reads A-kh1 (mi 4..7), bfr reused ; stage B-kh1(t+1) ----
#pragma unroll
        for (int q = 0; q < 4; ++q) afrB[q] = *(const short8*)(la + 16384 + aoff[q + 4]);
        if (pre) STAGE(nxb, Bb, 1, t + 1);
        PHASE_MID();
        __builtin_amdgcn_s_setprio(1);
#pragma unroll
        for (int q = 0; q < 4; ++q)
#pragma unroll
            for (int n = 0; n < 4; ++n)
                acc[q + 4][n] = __builtin_amdgcn_mfma_f32_16x16x32_bf16(
                    afrB[q], bfr[n], acc[q + 4][n], 0, 0, 0);
        __builtin_amdgcn_s_setprio(0);
        __builtin_amdgcn_sched_barrier(0);
        __builtin_amdgcn_s_barrier();
    }
#undef STAGE
#undef PHASE_MID

    // ---- fused LSTM epilogue (thread-local: ni == gate) ----
    float bias_v[4];
#pragma unroll
    for (int g = 0; g < 4; ++g)
        bias_v[g] = bias_p[bn * 256 + (wn >> 1) * 128 + g * 32 + (wn & 1) * 16 + col16];

    const int hc_g = bn * 64 + (wn >> 1) * 32 + (wn & 1) * 16 + col16;

#pragma unroll
    for (int mi = 0; mi < 8; ++mi) {
#pragma unroll
        for (int reg = 0; reg < 4; ++reg) {
            const int m_g = bm * 256 + wm * 128 + mi * 16 + quad * 4 + reg;
            float gi = acc[mi][0][reg] + bias_v[0];
            float gf = acc[mi][1][reg] + bias_v[1];
            float gg = acc[mi][2][reg] + bias_v[2];
            float go = acc[mi][3][reg] + bias_v[3];
            float iv = sigmoidf_(gi);
            float fv = sigmoidf_(gf);
            float gv = tanhf_(gg);
            float ov = sigmoidf_(go);
            float co = c_in[(size_t)m_g * H_DIM + hc_g];
            float cn = fv * co + iv * gv;
            float hn = ov * tanhf_(cn);
            out[(size_t)m_g * H_DIM + hc_g]      = hn;   // h_new
            out[BH + (size_t)m_g * H_DIM + hc_g] = cn;   // c_new
        }
    }
}

// ---------------------------------------------------------------------------
// Fallback path (validated R1 kernels) in case ws_size < 36 MB.
// ---------------------------------------------------------------------------
__global__ __launch_bounds__(256) void prep_weights_fb(
    const float* __restrict__ Wx, const float* __restrict__ Wh,
    const float* __restrict__ bx, const float* __restrict__ bh,
    __hip_bfloat16* __restrict__ Wt, float* __restrict__ bias_p) {
    __shared__ __hip_bfloat16 tile[32][33];
    const int bid = blockIdx.x;
    const int bk  = bid & 31;
    const int bn  = bid >> 5;
    const int t   = threadIdx.x;
    const int kb  = bk * 32, nb = bn * 32;
#pragma unroll
    for (int r = 0; r < 4; ++r) {
        int k_loc = r * 8 + (t >> 5);
        int n_loc = t & 31;
        int kg = kb + k_loc;
        float v = (kg < IN_DIM) ? Wx[(size_t)kg * N4H + nb + n_loc]
                                : Wh[(size_t)(kg - IN_DIM) * N4H + nb + n_loc];
        tile[k_loc][n_loc] = __float2bfloat16(v);
    }
    __syncthreads();
    {
        int n_loc = t >> 3;
        int k_loc = (t & 7) * 4;
        int ng = nb + n_loc;
        int g  = ng >> 9;
        int c  = ng & 511;
        int row_out = (c >> 5) * 128 + g * 32 + (c & 31);
        short4v v4;
        v4.x = *reinterpret_cast<short*>(&tile[k_loc + 0][n_loc]);
        v4.y = *reinterpret_cast<short*>(&tile[k_loc + 1][n_loc]);
        v4.z = *reinterpret_cast<short*>(&tile[k_loc + 2][n_loc]);
        v4.w = *reinterpret_cast<short*>(&tile[k_loc + 3][n_loc]);
        *(short4v*)&Wt[(size_t)row_out * K_DIM + kb + k_loc] = v4;
    }
    if (bid < 8) {
        int ng = bid * 256 + t;
        int g  = ng >> 9;
        int c  = ng & 511;
        int ro = (c >> 5) * 128 + g * 32 + (c & 31);
        bias_p[ro] = bx[ng] + bh[ng];
    }
}

__global__ __launch_bounds__(256, 3) void lstm_gemm_fb(
    const float* __restrict__ x, const float* __restrict__ h,
    const float* __restrict__ c_in,
    const __hip_bfloat16* __restrict__ Wt, const float* __restrict__ bias_p,
    float* __restrict__ out) {
    __shared__ __hip_bfloat16 lds_a[128 * 32];
    __shared__ __hip_bfloat16 lds_b[128 * 32];
    const int tid   = threadIdx.x;
    const int bn    = blockIdx.x & 15;
    const int bm    = blockIdx.x >> 4;
    const int w     = tid >> 6;
    const int lane  = tid & 63;
    const int col16 = lane & 15;
    const int quad  = lane >> 4;
    f32x4 acc[2][8];
#pragma unroll
    for (int mi = 0; mi < 2; ++mi)
#pragma unroll
        for (int ni = 0; ni < 8; ++ni)
            acc[mi][ni] = (f32x4){0.f, 0.f, 0.f, 0.f};
    const __hip_bfloat16* wt_base = Wt + (size_t)(bn * 128) * K_DIM;
    const int chunk0 = w * 2;
    const int e0     = chunk0 * 512 + lane * 8;
    const int bn_loc0 = e0 >> 5, bk_off0 = e0 & 31;
    const int e1     = (chunk0 + 1) * 512 + lane * 8;
    const int bn_loc1 = e1 >> 5, bk_off1 = e1 & 31;
    for (int kt = 0; kt < 32; ++kt) {
        const int kb = kt * 32;
        const float* aptr;
        int koff;
        if (kb < IN_DIM) { aptr = x; koff = kb; }
        else             { aptr = h; koff = kb - IN_DIM; }
        async_load16(wt_base + (size_t)bn_loc0 * K_DIM + kb + bk_off0,
                     (void*)(lds_b + chunk0 * 512));
        async_load16(wt_base + (size_t)bn_loc1 * K_DIM + kb + bk_off1,
                     (void*)(lds_b + (chunk0 + 1) * 512));
        float4 av[4];
#pragma unroll
        for (int j = 0; j < 4; ++j) {
            int cch = j * 256 + tid;
            int row = cch >> 3;
            int kq  = (cch & 7) * 4;
            av[j] = *(const float4*)(aptr + (size_t)(bm * 128 + row) * IN_DIM
                                     + koff + kq);
        }
#pragma unroll
        for (int j = 0; j < 4; ++j) {
            int cch = j * 256 + tid;
            int row = cch >> 3;
            int kq  = (cch & 7) * 4;
            short4v sv;
            sv.x = bf16bits(av[j].x);
            sv.y = bf16bits(av[j].y);
            sv.z = bf16bits(av[j].z);
            sv.w = bf16bits(av[j].w);
            *(short4v*)&lds_a[row * 32 + kq] = sv;
        }
        __syncthreads();
        short8 afr[2], bfr[8];
#pragma unroll
        for (int mi = 0; mi < 2; ++mi)
            afr[mi] = *(const short8*)&lds_a[(w * 32 + mi * 16 + col16) * 32 + quad * 8];
#pragma unroll
        for (int ni = 0; ni < 8; ++ni)
            bfr[ni] = *(const short8*)&lds_b[(ni * 16 + col16) * 32 + quad * 8];
#pragma unroll
        for (int mi = 0; mi < 2; ++mi)
#pragma unroll
            for (int ni = 0; ni < 8; ++ni)
                acc[mi][ni] = __builtin_amdgcn_mfma_f32_16x16x32_bf16(
                    afr[mi], bfr[ni], acc[mi][ni], 0, 0, 0);
        __syncthreads();
    }
    float bias_v[4][2];
#pragma unroll
    for (int g = 0; g < 4; ++g)
#pragma unroll
        for (int h2 = 0; h2 < 2; ++h2)
            bias_v[g][h2] = bias_p[bn * 128 + g * 32 + h2 * 16 + col16];
#pragma unroll
    for (int mi = 0; mi < 2; ++mi) {
#pragma unroll
        for (int reg = 0; reg < 4; ++reg) {
            const int m_g = bm * 128 + w * 32 + mi * 16 + quad * 4 + reg;
#pragma unroll
            for (int h2 = 0; h2 < 2; ++h2) {
                const int hc_g = bn * 32 + h2 * 16 + col16;
                float gi = acc[mi][0 + h2][reg] + bias_v[0][h2];
                float gf = acc[mi][2 + h2][reg] + bias_v[1][h2];
                float gg = acc[mi][4 + h2][reg] + bias_v[2][h2];
                float go = acc[mi][6 + h2][reg] + bias_v[3][h2];
                float iv = sigmoidf_(gi);
                float fv = sigmoidf_(gf);
                float gv = tanhf_(gg);
                float ov = sigmoidf_(go);
                float co = c_in[(size_t)m_g * H_DIM + hc_g];
                float cn = fv * co + iv * gv;
                float hn = ov * tanhf_(cn);
                out[(size_t)m_g * H_DIM + hc_g]      = hn;
                out[BH + (size_t)m_g * H_DIM + hc_g] = cn;
            }
        }
    }
}

extern "C" void kernel_launch(void* const* d_in, const int* in_sizes, int n_in,
                              void* d_out, int out_size, void* d_ws, size_t ws_size,
                              hipStream_t stream) {
    const float* x  = (const float*)d_in[0];
    const float* h  = (const float*)d_in[1];
    const float* c  = (const float*)d_in[2];
    const float* Wx = (const float*)d_in[3];
    const float* Wh = (const float*)d_in[4];
    const float* bx = (const float*)d_in[5];
    const float* bh = (const float*)d_in[6];

    const size_t wtBytes  = (size_t)N4H * K_DIM * 2;    // 4 MB
    const size_t axhBytes = (size_t)B_DIM * K_DIM * 2;  // 32 MB
    const size_t need     = wtBytes + axhBytes + (size_t)N4H * 4;

    if (ws_size >= need) {
        __hip_bfloat16* Wt  = (__hip_bfloat16*)d_ws;
        __hip_bfloat16* Axh = (__hip_bfloat16*)((char*)d_ws + wtBytes);
        float* bias_p = (float*)((char*)d_ws + wtBytes + axhBytes);
        prep_all<<<4096, 256, 0, stream>>>(Wx, Wh, bx, bh, x, h, Wt, Axh, bias_p);
        lstm_gemm256<<<512, 512, 0, stream>>>(c, Axh, Wt, bias_p, (float*)d_out);
    } else {
        __hip_bfloat16* Wt = (__hip_bfloat16*)d_ws;
        float* bias_p = (float*)((char*)d_ws + wtBytes);
        prep_weights_fb<<<2048, 256, 0, stream>>>(Wx, Wh, bx, bh, Wt, bias_p);
        lstm_gemm_fb<<<2048, 256, 0, stream>>>(x, h, c, Wt, bias_p, (float*)d_out);
    }
}

// Round 8
// 235.947 us; speedup vs baseline: 1.1963x; 1.0297x over previous
//
#include <hip/hip_runtime.h>
#include <hip/hip_bf16.h>

// Problem constants (fixed by the reference)
#define B_DIM   16384
#define IN_DIM  512
#define H_DIM   512
#define K_DIM   1024          // IN + H concatenated
#define N4H     2048          // 4*H
#define BH      (B_DIM * H_DIM)

typedef __attribute__((ext_vector_type(8))) short  short8;   // 8 bf16 = one MFMA operand
typedef __attribute__((ext_vector_type(4))) short  short4v;  // 4 bf16 = 8B write
typedef __attribute__((ext_vector_type(4))) float  f32x4;    // MFMA accumulator

__device__ inline void async_load16(const void* g, void* l) {
    __builtin_amdgcn_global_load_lds(
        (const __attribute__((address_space(1))) void*)g,
        (__attribute__((address_space(3)))       void*)l, 16, 0, 0);
}

__device__ inline short bf16bits(float f) {
    __hip_bfloat16 b = __float2bfloat16(f);
    return *reinterpret_cast<short*>(&b);
}

__device__ inline float sigmoidf_(float v) {
    return 1.0f / (1.0f + __expf(-v));
}
__device__ inline float tanhf_(float v) {
    v = fminf(fmaxf(v, -30.f), 30.f);
    float e = __expf(2.f * v);
    return (e - 1.f) / (e + 1.f);
}

// ---------------------------------------------------------------------------
// Combined prep: Wt gate-permuted bf16 (blocks [0,2048)) + Axh = bf16(x||h)
// (blocks [2048,6144), 4 rows each — 2x the parallelism of the prior 8-row
// version to push the 96MB stream closer to BW ceiling) + packed bias.
// ---------------------------------------------------------------------------
__global__ __launch_bounds__(256) void prep_all(
    const float* __restrict__ Wx, const float* __restrict__ Wh,
    const float* __restrict__ bx, const float* __restrict__ bh,
    const float* __restrict__ x,  const float* __restrict__ h,
    __hip_bfloat16* __restrict__ Wt, __hip_bfloat16* __restrict__ Axh,
    float* __restrict__ bias_p) {
    const int bid = blockIdx.x;
    const int t   = threadIdx.x;

    if (bid < 2048) {
        __shared__ __hip_bfloat16 tile[32][33];
        const int bk = bid & 31;
        const int bn = bid >> 5;
        const int kb = bk * 32, nb = bn * 32;
#pragma unroll
        for (int r = 0; r < 4; ++r) {
            int k_loc = r * 8 + (t >> 5);
            int n_loc = t & 31;
            int kg = kb + k_loc;
            float v = (kg < IN_DIM) ? Wx[(size_t)kg * N4H + nb + n_loc]
                                    : Wh[(size_t)(kg - IN_DIM) * N4H + nb + n_loc];
            tile[k_loc][n_loc] = __float2bfloat16(v);
        }
        __syncthreads();
        {
            int n_loc = t >> 3;
            int k_loc = (t & 7) * 4;
            int ng = nb + n_loc;
            int g  = ng >> 9;
            int c  = ng & 511;
            int row_out = (c >> 5) * 128 + g * 32 + (c & 31);
            short4v v4;
            v4.x = *reinterpret_cast<short*>(&tile[k_loc + 0][n_loc]);
            v4.y = *reinterpret_cast<short*>(&tile[k_loc + 1][n_loc]);
            v4.z = *reinterpret_cast<short*>(&tile[k_loc + 2][n_loc]);
            v4.w = *reinterpret_cast<short*>(&tile[k_loc + 3][n_loc]);
            *(short4v*)&Wt[(size_t)row_out * K_DIM + kb + k_loc] = v4;
        }
        if (bid < 8) {
            int ng = bid * 256 + t;
            int g  = ng >> 9;
            int c  = ng & 511;
            int ro = (c >> 5) * 128 + g * 32 + (c & 31);
            bias_p[ro] = bx[ng] + bh[ng];
        }
    } else {
        const int ab = bid - 2048;              // 0..4095, 4 rows each
        const int kq = t;                       // float4 index within row
        const float* src = (kq < 128) ? (x + kq * 4)
                                      : (h + (size_t)(kq - 128) * 4);
#pragma unroll
        for (int j = 0; j < 4; ++j) {
            int m = ab * 4 + j;
            float4 v = *(const float4*)(src + (size_t)m * 512);
            short4v sv;
            sv.x = bf16bits(v.x);
            sv.y = bf16bits(v.y);
            sv.z = bf16bits(v.z);
            sv.w = bf16bits(v.w);
            *(short4v*)&Axh[(size_t)m * K_DIM + kq * 4] = sv;
        }
    }
}

// ---------------------------------------------------------------------------
// 2-phase counted-vmcnt 256x256 GEMM + fused LSTM epilogue.
// r7 post-mortem: 4 phases/K-tile (9 barriers) ran at 110us = same as the
// 2-barrier r0 structure -> barrier reconvergence + SGB-pinned addr VALU
// dominated. This round halves the phase count:
//   per K-tile: 2 phases, each {12 ds_read_b128 || stage 4 gload_lds} ->
//     SGB -> barrier -> lgkmcnt(0) -> SGB -> setprio(1) 32 MFMA setprio(0)
//     -> SGB -> [counted vmcnt] -> barrier
//   vmcnt FIFO (per wave, 4 loads staged per phase, verified):
//     boundary(t):  outstanding {kh0,kh1}(t)=8      -> vmcnt(4) drains kh0(t)
//     end-ph0(t):   outstanding kh1(t)+kh0(t+1)=8   -> vmcnt(4) drains kh1(t)
//     (t=15: vmcnt(0) — no new stages in flight).  Never 0 mid-loop;
//     drain-BEFORE-barrier at both points -> cross-wave safe.
//   bn = blockIdx&7 = XCD id (round-robin assumption): each XCD's 512KB
//     B-slice stays L2-resident; A panels stream via L3 (speed-only).
//   LDS [dbuf][kh][256r][32k], r0-validated additive rotation swizzle,
//     pre-swizzled global source, linear DMA dest. Accumulation order per
//     acc element identical to r7 (kh0 then kh1) -> bit-identical numerics.
// ---------------------------------------------------------------------------
__global__ __launch_bounds__(512, 2) void lstm_gemm256(
    const float* __restrict__ c_in,
    const __hip_bfloat16* __restrict__ Axh,
    const __hip_bfloat16* __restrict__ Wt,
    const float* __restrict__ bias_p,
    float* __restrict__ out) {
    __shared__ __align__(16) __hip_bfloat16 lds_a[2][16384];  // [dbuf][kh*8192+..]
    __shared__ __align__(16) __hip_bfloat16 lds_b[2][16384];

    const int tid   = threadIdx.x;
    const int w     = tid >> 6;          // wave 0..7
    const int lane  = tid & 63;
    const int col16 = lane & 15;
    const int quad  = lane >> 4;
    const int wm    = w >> 2;            // 0..1  (M half: 128 rows)
    const int wn    = w & 3;             // 0..3  (N quarter: 16ch x 4 gates)

    // bn pinned to XCD (jb&7 == XCD under round-robin dispatch)
    const int jb = blockIdx.x;           // 0..511
    const int bn = jb & 7;               // 0..7   (256 Wt rows, 512KB slice)
    const int bm = jb >> 3;              // 0..63  (256 A rows)

    f32x4 acc[8][4];
#pragma unroll
    for (int mi = 0; mi < 8; ++mi)
#pragma unroll
        for (int ni = 0; ni < 4; ++ni)
            acc[mi][ni] = (f32x4){0.f, 0.f, 0.f, 0.f};

    const __hip_bfloat16* Ab = Axh + (size_t)bm * 256 * K_DIM;
    const __hip_bfloat16* Bb = Wt  + (size_t)bn * 256 * K_DIM;

    // staging: granule = j*512 + tid (16B) -> row j*128 + (tid>>2), phys slot
    // pg = tid&3 holds logical k-octet lq = (pg-(r>>1))&3 (inverse rotation).
    const int lq = ((tid & 3) - ((tid >> 3) & 3)) & 3;

#define STAGE(LDSBUF, GBASE, KH, KT)  do {                                     \
    const __hip_bfloat16* _s = (GBASE) + (size_t)(tid >> 2) * K_DIM            \
                               + (KT) * 64 + (KH) * 32 + lq * 8;               \
    char* _d = (char*)(LDSBUF) + (KH) * 16384 + w * 1024;                      \
    async_load16(_s,                       _d);                                \
    async_load16(_s + (size_t)128 * K_DIM, _d + 8192);                         \
  } while (0)

    // fragment-read byte offsets (r0-validated additive-rotation, 0 conflicts
    // measured r4/r7): byte = row*64 + ((quad+((row>>1)&3))&3)*16, +16384/kh.
    int aoff[8], boff[4];
#pragma unroll
    for (int mi = 0; mi < 8; ++mi) {
        int r = wm * 128 + mi * 16 + col16;
        aoff[mi] = r * 64 + ((quad + ((r >> 1) & 3)) & 3) * 16;
    }
#pragma unroll
    for (int ni = 0; ni < 4; ++ni) {
        int r = (wn >> 1) * 128 + ni * 32 + (wn & 1) * 16 + col16;
        boff[ni] = r * 64 + ((quad + ((r >> 1) & 3)) & 3) * 16;
    }

    // prologue: stage tile 0 (FIFO: {A,B}-kh0 then {A,B}-kh1)
    STAGE(lds_a[0], Ab, 0, 0);
    STAGE(lds_b[0], Bb, 0, 0);
    STAGE(lds_a[0], Ab, 1, 0);
    STAGE(lds_b[0], Bb, 1, 0);

    for (int t = 0; t < 16; ++t) {
        const int cur = t & 1;
        const char* la = (const char*)lds_a[cur];
        const char* lb = (const char*)lds_b[cur];
        __hip_bfloat16* nxa = lds_a[cur ^ 1];
        __hip_bfloat16* nxb = lds_b[cur ^ 1];
        const bool pre = (t < 15);

        // boundary: drain {A,B}-kh0(t) (oldest 4), keep kh1(t) in flight
        asm volatile("s_waitcnt vmcnt(4)" ::: "memory");
        __builtin_amdgcn_s_barrier();

        short8 afr[8], bfr[4];

        // ---- phase 0 : kh0 (12 ds_reads -> 32 MFMA) ; stage {A,B}-kh0(t+1)
#pragma unroll
        for (int q = 0; q < 8; ++q) afr[q] = *(const short8*)(la + aoff[q]);
#pragma unroll
        for (int n = 0; n < 4; ++n) bfr[n] = *(const short8*)(lb + boff[n]);
        if (pre) { STAGE(nxa, Ab, 0, t + 1); STAGE(nxb, Bb, 0, t + 1); }
        __builtin_amdgcn_sched_barrier(0);
        __builtin_amdgcn_s_barrier();
        asm volatile("s_waitcnt lgkmcnt(0)" ::: "memory");
        __builtin_amdgcn_sched_barrier(0);
        __builtin_amdgcn_s_setprio(1);
#pragma unroll
        for (int q = 0; q < 8; ++q)
#pragma unroll
            for (int n = 0; n < 4; ++n)
                acc[q][n] = __builtin_amdgcn_mfma_f32_16x16x32_bf16(
                    afr[q], bfr[n], acc[q][n], 0, 0, 0);
        __builtin_amdgcn_s_setprio(0);
        __builtin_amdgcn_sched_barrier(0);
        // drain kh1(t) (needed by phase 1), keep kh0(t+1) flying
        if (pre) asm volatile("s_waitcnt vmcnt(4)" ::: "memory");
        else     asm volatile("s_waitcnt vmcnt(0)" ::: "memory");
        __builtin_amdgcn_s_barrier();

        // ---- phase 1 : kh1 ; stage {A,B}-kh1(t+1) ----
#pragma unroll
        for (int q = 0; q < 8; ++q) afr[q] = *(const short8*)(la + 16384 + aoff[q]);
#pragma unroll
        for (int n = 0; n < 4; ++n) bfr[n] = *(const short8*)(lb + 16384 + boff[n]);
        if (pre) { STAGE(nxa, Ab, 1, t + 1); STAGE(nxb, Bb, 1, t + 1); }
        __builtin_amdgcn_sched_barrier(0);
        __builtin_amdgcn_s_barrier();
        asm volatile("s_waitcnt lgkmcnt(0)" ::: "memory");
        __builtin_amdgcn_sched_barrier(0);
        __builtin_amdgcn_s_setprio(1);
#pragma unroll
        for (int q = 0; q < 8; ++q)
#pragma unroll
            for (int n = 0; n < 4; ++n)
                acc[q][n] = __builtin_amdgcn_mfma_f32_16x16x32_bf16(
                    afr[q], bfr[n], acc[q][n], 0, 0, 0);
        __builtin_amdgcn_s_setprio(0);
        __builtin_amdgcn_sched_barrier(0);
        __builtin_amdgcn_s_barrier();
    }
#undef STAGE

    // ---- fused LSTM epilogue (thread-local: ni == gate) ----
    float bias_v[4];
#pragma unroll
    for (int g = 0; g < 4; ++g)
        bias_v[g] = bias_p[bn * 256 + (wn >> 1) * 128 + g * 32 + (wn & 1) * 16 + col16];

    const int hc_g = bn * 64 + (wn >> 1) * 32 + (wn & 1) * 16 + col16;

#pragma unroll
    for (int mi = 0; mi < 8; ++mi) {
#pragma unroll
        for (int reg = 0; reg < 4; ++reg) {
            const int m_g = bm * 256 + wm * 128 + mi * 16 + quad * 4 + reg;
            float gi = acc[mi][0][reg] + bias_v[0];
            float gf = acc[mi][1][reg] + bias_v[1];
            float gg = acc[mi][2][reg] + bias_v[2];
            float go = acc[mi][3][reg] + bias_v[3];
            float iv = sigmoidf_(gi);
            float fv = sigmoidf_(gf);
            float gv = tanhf_(gg);
            float ov = sigmoidf_(go);
            float co = c_in[(size_t)m_g * H_DIM + hc_g];
            float cn = fv * co + iv * gv;
            float hn = ov * tanhf_(cn);
            out[(size_t)m_g * H_DIM + hc_g]      = hn;   // h_new
            out[BH + (size_t)m_g * H_DIM + hc_g] = cn;   // c_new
        }
    }
}

// ---------------------------------------------------------------------------
// Fallback path (validated R1 kernels) in case ws_size < 36 MB.
// ---------------------------------------------------------------------------
__global__ __launch_bounds__(256) void prep_weights_fb(
    const float* __restrict__ Wx, const float* __restrict__ Wh,
    const float* __restrict__ bx, const float* __restrict__ bh,
    __hip_bfloat16* __restrict__ Wt, float* __restrict__ bias_p) {
    __shared__ __hip_bfloat16 tile[32][33];
    const int bid = blockIdx.x;
    const int bk  = bid & 31;
    const int bn  = bid >> 5;
    const int t   = threadIdx.x;
    const int kb  = bk * 32, nb = bn * 32;
#pragma unroll
    for (int r = 0; r < 4; ++r) {
        int k_loc = r * 8 + (t >> 5);
        int n_loc = t & 31;
        int kg = kb + k_loc;
        float v = (kg < IN_DIM) ? Wx[(size_t)kg * N4H + nb + n_loc]
                                : Wh[(size_t)(kg - IN_DIM) * N4H + nb + n_loc];
        tile[k_loc][n_loc] = __float2bfloat16(v);
    }
    __syncthreads();
    {
        int n_loc = t >> 3;
        int k_loc = (t & 7) * 4;
        int ng = nb + n_loc;
        int g  = ng >> 9;
        int c  = ng & 511;
        int row_out = (c >> 5) * 128 + g * 32 + (c & 31);
        short4v v4;
        v4.x = *reinterpret_cast<short*>(&tile[k_loc + 0][n_loc]);
        v4.y = *reinterpret_cast<short*>(&tile[k_loc + 1][n_loc]);
        v4.z = *reinterpret_cast<short*>(&tile[k_loc + 2][n_loc]);
        v4.w = *reinterpret_cast<short*>(&tile[k_loc + 3][n_loc]);
        *(short4v*)&Wt[(size_t)row_out * K_DIM + kb + k_loc] = v4;
    }
    if (bid < 8) {
        int ng = bid * 256 + t;
        int g  = ng >> 9;
        int c  = ng & 511;
        int ro = (c >> 5) * 128 + g * 32 + (c & 31);
        bias_p[ro] = bx[ng] + bh[ng];
    }
}

__global__ __launch_bounds__(256, 3) void lstm_gemm_fb(
    const float* __restrict__ x, const float* __restrict__ h,
    const float* __restrict__ c_in,
    const __hip_bfloat16* __restrict__ Wt, const float* __restrict__ bias_p,
    float* __restrict__ out) {
    __shared__ __hip_bfloat16 lds_a[128 * 32];
    __shared__ __hip_bfloat16 lds_b[128 * 32];
    const int tid   = threadIdx.x;
    const int bn    = blockIdx.x & 15;
    const int bm    = blockIdx.x >> 4;
    const int w     = tid >> 6;
    const int lane  = tid & 63;
    const int col16 = lane & 15;
    const int quad  = lane >> 4;
    f32x4 acc[2][8];
#pragma unroll
    for (int mi = 0; mi < 2; ++mi)
#pragma unroll
        for (int ni = 0; ni < 8; ++ni)
            acc[mi][ni] = (f32x4){0.f, 0.f, 0.f, 0.f};
    const __hip_bfloat16* wt_base = Wt + (size_t)(bn * 128) * K_DIM;
    const int chunk0 = w * 2;
    const int e0     = chunk0 * 512 + lane * 8;
    const int bn_loc0 = e0 >> 5, bk_off0 = e0 & 31;
    const int e1     = (chunk0 + 1) * 512 + lane * 8;
    const int bn_loc1 = e1 >> 5, bk_off1 = e1 & 31;
    for (int kt = 0; kt < 32; ++kt) {
        const int kb = kt * 32;
        const float* aptr;
        int koff;
        if (kb < IN_DIM) { aptr = x; koff = kb; }
        else             { aptr = h; koff = kb - IN_DIM; }
        async_load16(wt_base + (size_t)bn_loc0 * K_DIM + kb + bk_off0,
                     (void*)(lds_b + chunk0 * 512));
        async_load16(wt_base + (size_t)bn_loc1 * K_DIM + kb + bk_off1,
                     (void*)(lds_b + (chunk0 + 1) * 512));
        float4 av[4];
#pragma unroll
        for (int j = 0; j < 4; ++j) {
            int cch = j * 256 + tid;
            int row = cch >> 3;
            int kq  = (cch & 7) * 4;
            av[j] = *(const float4*)(aptr + (size_t)(bm * 128 + row) * IN_DIM
                                     + koff + kq);
        }
#pragma unroll
        for (int j = 0; j < 4; ++j) {
            int cch = j * 256 + tid;
            int row = cch >> 3;
            int kq  = (cch & 7) * 4;
            short4v sv;
            sv.x = bf16bits(av[j].x);
            sv.y = bf16bits(av[j].y);
            sv.z = bf16bits(av[j].z);
            sv.w = bf16bits(av[j].w);
            *(short4v*)&lds_a[row * 32 + kq] = sv;
        }
        __syncthreads();
        short8 afr[2], bfr[8];
#pragma unroll
        for (int mi = 0; mi < 2; ++mi)
            afr[mi] = *(const short8*)&lds_a[(w * 32 + mi * 16 + col16) * 32 + quad * 8];
#pragma unroll
        for (int ni = 0; ni < 8; ++ni)
            bfr[ni] = *(const short8*)&lds_b[(ni * 16 + col16) * 32 + quad * 8];
#pragma unroll
        for (int mi = 0; mi < 2; ++mi)
#pragma unroll
            for (int ni = 0; ni < 8; ++ni)
                acc[mi][ni] = __builtin_amdgcn_mfma_f32_16x16x32_bf16(
                    afr[mi], bfr[ni], acc[mi][ni], 0, 0, 0);
        __syncthreads();
    }
    float bias_v[4][2];
#pragma unroll
    for (int g = 0; g < 4; ++g)
#pragma unroll
        for (int h2 = 0; h2 < 2; ++h2)
            bias_v[g][h2] = bias_p[bn * 128 + g * 32 + h2 * 16 + col16];
#pragma unroll
    for (int mi = 0; mi < 2; ++mi) {
#pragma unroll
        for (int reg = 0; reg < 4; ++reg) {
            const int m_g = bm * 128 + w * 32 + mi * 16 + quad * 4 + reg;
#pragma unroll
            for (int h2 = 0; h2 < 2; ++h2) {
                const int hc_g = bn * 32 + h2 * 16 + col16;
                float gi = acc[mi][0 + h2][reg] + bias_v[0][h2];
                float gf = acc[mi][2 + h2][reg] + bias_v[1][h2];
                float gg = acc[mi][4 + h2][reg] + bias_v[2][h2];
                float go = acc[mi][6 + h2][reg] + bias_v[3][h2];
                float iv = sigmoidf_(gi);
                float fv = sigmoidf_(gf);
                float gv = tanhf_(gg);
                float ov = sigmoidf_(go);
                float co = c_in[(size_t)m_g * H_DIM + hc_g];
                float cn = fv * co + iv * gv;
                float hn = ov * tanhf_(cn);
                out[(size_t)m_g * H_DIM + hc_g]      = hn;
                out[BH + (size_t)m_g * H_DIM + hc_g] = cn;
            }
        }
    }
}

extern "C" void kernel_launch(void* const* d_in, const int* in_sizes, int n_in,
                              void* d_out, int out_size, void* d_ws, size_t ws_size,
                              hipStream_t stream) {
    const float* x  = (const float*)d_in[0];
    const float* h  = (const float*)d_in[1];
    const float* c  = (const float*)d_in[2];
    const float* Wx = (const float*)d_in[3];
    const float* Wh = (const float*)d_in[4];
    const float* bx = (const float*)d_in[5];
    const float* bh = (const float*)d_in[6];

    const size_t wtBytes  = (size_t)N4H * K_DIM * 2;    // 4 MB
    const size_t axhBytes = (size_t)B_DIM * K_DIM * 2;  // 32 MB
    const size_t need     = wtBytes + axhBytes + (size_t)N4H * 4;

    if (ws_size >= need) {
        __hip_bfloat16* Wt  = (__hip_bfloat16*)d_ws;
        __hip_bfloat16* Axh = (__hip_bfloat16*)((char*)d_ws + wtBytes);
        float* bias_p = (float*)((char*)d_ws + wtBytes + axhBytes);
        prep_all<<<6144, 256, 0, stream>>>(Wx, Wh, bx, bh, x, h, Wt, Axh, bias_p);
        lstm_gemm256<<<512, 512, 0, stream>>>(c, Axh, Wt, bias_p, (float*)d_out);
    } else {
        __hip_bfloat16* Wt = (__hip_bfloat16*)d_ws;
        float* bias_p = (float*)((char*)d_ws + wtBytes);
        prep_weights_fb<<<2048, 256, 0, stream>>>(Wx, Wh, bx, bh, Wt, bias_p);
        lstm_gemm_fb<<<2048, 256, 0, stream>>>(x, h, c, Wt, bias_p, (float*)d_out);
    }
}

// Round 11
// 224.341 us; speedup vs baseline: 1.2582x; 1.0517x over previous
//
#include <hip/hip_runtime.h>
#include <hip/hip_bf16.h>

// Problem constants (fixed by the reference)
#define B_DIM   16384
#define IN_DIM  512
#define H_DIM   512
#define K_DIM   1024          // IN + H concatenated
#define N4H     2048          // 4*H
#define BH      (B_DIM * H_DIM)

typedef __attribute__((ext_vector_type(8))) short  short8;   // 8 bf16 = one MFMA operand
typedef __attribute__((ext_vector_type(4))) short  short4v;  // 4 bf16 = 8B write
typedef __attribute__((ext_vector_type(4))) float  f32x4;    // MFMA accumulator

__device__ inline void async_load16(const void* g, void* l) {
    __builtin_amdgcn_global_load_lds(
        (const __attribute__((address_space(1))) void*)g,
        (__attribute__((address_space(3)))       void*)l, 16, 0, 0);
}

__device__ inline short bf16bits(float f) {
    __hip_bfloat16 b = __float2bfloat16(f);
    return *reinterpret_cast<short*>(&b);
}

__device__ inline float sigmoidf_(float v) {
    return 1.0f / (1.0f + __expf(-v));
}
__device__ inline float tanhf_(float v) {
    v = fminf(fmaxf(v, -30.f), 30.f);
    float e = __expf(2.f * v);
    return (e - 1.f) / (e + 1.f);
}

// ---------------------------------------------------------------------------
// Combined prep: Wt gate-permuted bf16 (blocks [0,2048)) + Axh = bf16(x||h)
// (blocks [2048,6144), 4 rows each) + packed bias.
// ---------------------------------------------------------------------------
__global__ __launch_bounds__(256) void prep_all(
    const float* __restrict__ Wx, const float* __restrict__ Wh,
    const float* __restrict__ bx, const float* __restrict__ bh,
    const float* __restrict__ x,  const float* __restrict__ h,
    __hip_bfloat16* __restrict__ Wt, __hip_bfloat16* __restrict__ Axh,
    float* __restrict__ bias_p) {
    const int bid = blockIdx.x;
    const int t   = threadIdx.x;

    if (bid < 2048) {
        __shared__ __hip_bfloat16 tile[32][33];
        const int bk = bid & 31;
        const int bn = bid >> 5;
        const int kb = bk * 32, nb = bn * 32;
#pragma unroll
        for (int r = 0; r < 4; ++r) {
            int k_loc = r * 8 + (t >> 5);
            int n_loc = t & 31;
            int kg = kb + k_loc;
            float v = (kg < IN_DIM) ? Wx[(size_t)kg * N4H + nb + n_loc]
                                    : Wh[(size_t)(kg - IN_DIM) * N4H + nb + n_loc];
            tile[k_loc][n_loc] = __float2bfloat16(v);
        }
        __syncthreads();
        {
            int n_loc = t >> 3;
            int k_loc = (t & 7) * 4;
            int ng = nb + n_loc;
            int g  = ng >> 9;
            int c  = ng & 511;
            int row_out = (c >> 5) * 128 + g * 32 + (c & 31);
            short4v v4;
            v4.x = *reinterpret_cast<short*>(&tile[k_loc + 0][n_loc]);
            v4.y = *reinterpret_cast<short*>(&tile[k_loc + 1][n_loc]);
            v4.z = *reinterpret_cast<short*>(&tile[k_loc + 2][n_loc]);
            v4.w = *reinterpret_cast<short*>(&tile[k_loc + 3][n_loc]);
            *(short4v*)&Wt[(size_t)row_out * K_DIM + kb + k_loc] = v4;
        }
        if (bid < 8) {
            int ng = bid * 256 + t;
            int g  = ng >> 9;
            int c  = ng & 511;
            int ro = (c >> 5) * 128 + g * 32 + (c & 31);
            bias_p[ro] = bx[ng] + bh[ng];
        }
    } else {
        const int ab = bid - 2048;              // 0..4095, 4 rows each
        const int kq = t;                       // float4 index within row
        const float* src = (kq < 128) ? (x + kq * 4)
                                      : (h + (size_t)(kq - 128) * 4);
#pragma unroll
        for (int j = 0; j < 4; ++j) {
            int m = ab * 4 + j;
            float4 v = *(const float4*)(src + (size_t)m * 512);
            short4v sv;
            sv.x = bf16bits(v.x);
            sv.y = bf16bits(v.y);
            sv.z = bf16bits(v.z);
            sv.w = bf16bits(v.w);
            *(short4v*)&Axh[(size_t)m * K_DIM + kq * 4] = sv;
        }
    }
}

// ---------------------------------------------------------------------------
// ILP-overlapped 256x256 GEMM + fused LSTM epilogue (round 9/10/11).
// r0/r7/r8 post-mortem: every barrier-phase variant serialized the LDS pipe
// (2300cy/K-tile) against the MFMA pipe (2480cy/K-tile) -> ~7600cy/tile
// measured. This version overlaps them with pure ILP and NO schedule pinning:
//   per K-tile: {24 ds_reads: ph0 frags then ph1 frags, separate regs} ->
//   {8 gload_lds for tile t+1} -> MFMA ph0 (compiler's fine lgkmcnt lets it
//   start when ph0's 12 reads land; LDS pipe processes ph1's reads UNDER it)
//   -> MFMA ph1 -> __syncthreads().
// __syncthreads' vmcnt(0)+lgkmcnt(0)+barrier is exactly the tile boundary
// semantics: DMA(t+1) has ~2500cy MFMA cover (> ~900cy HBM latency) so the
// drain is cheap, and cross-wave visibility/WAR safety is trivial.
// No inline-asm waits, no sched_barriers: the compiler schedules freely
// (and may sink the ph1 reads to manage VGPR pressure).
//   - 512 blocks, XCD mapping (r7-validated, FETCH 66MB): xcd=jb&7,
//     bm=xcd*8+(jb>>3>>3), bn=(jb>>3)&7
//   - LDS [dbuf][kh][256r][32k] per array = 128KB; r0-validated additive
//     rotation swizzle (0 conflicts measured r4/r7/r8), pre-swizzled global
//     source, linear DMA dest; accumulation order unchanged (kh0 then kh1).
// ---------------------------------------------------------------------------
__global__ __launch_bounds__(512, 2) void lstm_gemm256(
    const float* __restrict__ c_in,
    const __hip_bfloat16* __restrict__ Axh,
    const __hip_bfloat16* __restrict__ Wt,
    const float* __restrict__ bias_p,
    float* __restrict__ out) {
    __shared__ __align__(16) __hip_bfloat16 lds_a[2][16384];  // [dbuf][kh*8192+..]
    __shared__ __align__(16) __hip_bfloat16 lds_b[2][16384];

    const int tid   = threadIdx.x;
    const int w     = tid >> 6;          // wave 0..7
    const int lane  = tid & 63;
    const int col16 = lane & 15;
    const int quad  = lane >> 4;
    const int wm    = w >> 2;            // 0..1  (M half: 128 rows)
    const int wn    = w & 3;             // 0..3  (N quarter: 16ch x 4 gates)

    // r7-validated XCD-aware mapping (FETCH ~66MB): per-XCD 8bm x 8bn panel
    const int jb    = blockIdx.x;
    const int xcd   = jb & 7;
    const int local = jb >> 3;                   // 0..63
    const int bm    = xcd * 8 + (local >> 3);    // 0..63  (256 A rows each)
    const int bn    = local & 7;                 // 0..7   (256 Wt rows each)

    f32x4 acc[8][4];
#pragma unroll
    for (int mi = 0; mi < 8; ++mi)
#pragma unroll
        for (int ni = 0; ni < 4; ++ni)
            acc[mi][ni] = (f32x4){0.f, 0.f, 0.f, 0.f};

    const __hip_bfloat16* Ab = Axh + (size_t)bm * 256 * K_DIM;
    const __hip_bfloat16* Bb = Wt  + (size_t)bn * 256 * K_DIM;

    // staging: granule = j*512 + tid (16B) -> row j*128 + (tid>>2), phys slot
    // pg = tid&3 holds logical k-octet lq = (pg-(r>>1))&3 (inverse rotation).
    const int lq = ((tid & 3) - ((tid >> 3) & 3)) & 3;

#define STAGE(LDSBUF, GBASE, KH, KT)  do {                                     \
    const __hip_bfloat16* _s = (GBASE) + (size_t)(tid >> 2) * K_DIM            \
                               + (KT) * 64 + (KH) * 32 + lq * 8;               \
    char* _d = (char*)(LDSBUF) + (KH) * 16384 + w * 1024;                      \
    async_load16(_s,                       _d);                                \
    async_load16(_s + (size_t)128 * K_DIM, _d + 8192);                         \
  } while (0)

    // fragment-read byte offsets (r0-validated additive-rotation, 0 conflicts
    // measured r4/r7/r8): byte = row*64 + ((quad+((row>>1)&3))&3)*16; +16384/kh
    int aoff[8], boff[4];
#pragma unroll
    for (int mi = 0; mi < 8; ++mi) {
        int r = wm * 128 + mi * 16 + col16;
        aoff[mi] = r * 64 + ((quad + ((r >> 1) & 3)) & 3) * 16;
    }
#pragma unroll
    for (int ni = 0; ni < 4; ++ni) {
        int r = (wn >> 1) * 128 + ni * 32 + (wn & 1) * 16 + col16;
        boff[ni] = r * 64 + ((quad + ((r >> 1) & 3)) & 3) * 16;
    }

    // prologue: stage tile 0 into buf 0, publish
    STAGE(lds_a[0], Ab, 0, 0);
    STAGE(lds_b[0], Bb, 0, 0);
    STAGE(lds_a[0], Ab, 1, 0);
    STAGE(lds_b[0], Bb, 1, 0);
    __syncthreads();

    for (int t = 0; t < 16; ++t) {
        const int cur = t & 1;
        const char* la = (const char*)lds_a[cur];
        const char* lb = (const char*)lds_b[cur];
        __hip_bfloat16* nxa = lds_a[cur ^ 1];
        __hip_bfloat16* nxb = lds_b[cur ^ 1];

        // all 24 fragment reads up front: ph0 (kh0) first, ph1 (kh1) second.
        short8 a0[8], b0[4], a1[8], b1[4];
#pragma unroll
        for (int q = 0; q < 8; ++q) a0[q] = *(const short8*)(la + aoff[q]);
#pragma unroll
        for (int n = 0; n < 4; ++n) b0[n] = *(const short8*)(lb + boff[n]);
#pragma unroll
        for (int q = 0; q < 8; ++q) a1[q] = *(const short8*)(la + 16384 + aoff[q]);
#pragma unroll
        for (int n = 0; n < 4; ++n) b1[n] = *(const short8*)(lb + 16384 + boff[n]);

        // stage tile t+1 (8 DMA loads) — drained by this iteration's closing
        // __syncthreads, with the full MFMA region (~2500cy) as cover.
        if (t < 15) {
            STAGE(nxa, Ab, 0, t + 1);
            STAGE(nxb, Bb, 0, t + 1);
            STAGE(nxa, Ab, 1, t + 1);
            STAGE(nxb, Bb, 1, t + 1);
        }

        // MFMA ph0: starts when a0/b0 land (fine lgkmcnt); the LDS pipe
        // retires a1/b1 underneath it.
        __builtin_amdgcn_s_setprio(1);
#pragma unroll
        for (int q = 0; q < 8; ++q)
#pragma unroll
            for (int n = 0; n < 4; ++n)
                acc[q][n] = __builtin_amdgcn_mfma_f32_16x16x32_bf16(
                    a0[q], b0[n], acc[q][n], 0, 0, 0);
        // MFMA ph1
#pragma unroll
        for (int q = 0; q < 8; ++q)
#pragma unroll
            for (int n = 0; n < 4; ++n)
                acc[q][n] = __builtin_amdgcn_mfma_f32_16x16x32_bf16(
                    a1[q], b1[n], acc[q][n], 0, 0, 0);
        __builtin_amdgcn_s_setprio(0);

        // tile boundary: vmcnt(0)+lgkmcnt(0)+barrier (exact semantics needed)
        __syncthreads();
    }
#undef STAGE

    // ---- fused LSTM epilogue (thread-local: ni == gate) ----
    float bias_v[4];
#pragma unroll
    for (int g = 0; g < 4; ++g)
        bias_v[g] = bias_p[bn * 256 + (wn >> 1) * 128 + g * 32 + (wn & 1) * 16 + col16];

    const int hc_g = bn * 64 + (wn >> 1) * 32 + (wn & 1) * 16 + col16;

#pragma unroll
    for (int mi = 0; mi < 8; ++mi) {
#pragma unroll
        for (int reg = 0; reg < 4; ++reg) {
            const int m_g = bm * 256 + wm * 128 + mi * 16 + quad * 4 + reg;
            float gi = acc[mi][0][reg] + bias_v[0];
            float gf = acc[mi][1][reg] + bias_v[1];
            float gg = acc[mi][2][reg] + bias_v[2];
            float go = acc[mi][3][reg] + bias_v[3];
            float iv = sigmoidf_(gi);
            float fv = sigmoidf_(gf);
            float gv = tanhf_(gg);
            float ov = sigmoidf_(go);
            float co = c_in[(size_t)m_g * H_DIM + hc_g];
            float cn = fv * co + iv * gv;
            float hn = ov * tanhf_(cn);
            out[(size_t)m_g * H_DIM + hc_g]      = hn;   // h_new
            out[BH + (size_t)m_g * H_DIM + hc_g] = cn;   // c_new
        }
    }
}

// ---------------------------------------------------------------------------
// Fallback path (validated R1 kernels) in case ws_size < 36 MB.
// ---------------------------------------------------------------------------
__global__ __launch_bounds__(256) void prep_weights_fb(
    const float* __restrict__ Wx, const float* __restrict__ Wh,
    const float* __restrict__ bx, const float* __restrict__ bh,
    __hip_bfloat16* __restrict__ Wt, float* __restrict__ bias_p) {
    __shared__ __hip_bfloat16 tile[32][33];
    const int bid = blockIdx.x;
    const int bk  = bid & 31;
    const int bn  = bid >> 5;
    const int t   = threadIdx.x;
    const int kb  = bk * 32, nb = bn * 32;
#pragma unroll
    for (int r = 0; r < 4; ++r) {
        int k_loc = r * 8 + (t >> 5);
        int n_loc = t & 31;
        int kg = kb + k_loc;
        float v = (kg < IN_DIM) ? Wx[(size_t)kg * N4H + nb + n_loc]
                                : Wh[(size_t)(kg - IN_DIM) * N4H + nb + n_loc];
        tile[k_loc][n_loc] = __float2bfloat16(v);
    }
    __syncthreads();
    {
        int n_loc = t >> 3;
        int k_loc = (t & 7) * 4;
        int ng = nb + n_loc;
        int g  = ng >> 9;
        int c  = ng & 511;
        int row_out = (c >> 5) * 128 + g * 32 + (c & 31);
        short4v v4;
        v4.x = *reinterpret_cast<short*>(&tile[k_loc + 0][n_loc]);
        v4.y = *reinterpret_cast<short*>(&tile[k_loc + 1][n_loc]);
        v4.z = *reinterpret_cast<short*>(&tile[k_loc + 2][n_loc]);
        v4.w = *reinterpret_cast<short*>(&tile[k_loc + 3][n_loc]);
        *(short4v*)&Wt[(size_t)row_out * K_DIM + kb + k_loc] = v4;
    }
    if (bid < 8) {
        int ng = bid * 256 + t;
        int g  = ng >> 9;
        int c  = ng & 511;
        int ro = (c >> 5) * 128 + g * 32 + (c & 31);
        bias_p[ro] = bx[ng] + bh[ng];
    }
}

__global__ __launch_bounds__(256, 3) void lstm_gemm_fb(
    const float* __restrict__ x, const float* __restrict__ h,
    const float* __restrict__ c_in,
    const __hip_bfloat16* __restrict__ Wt, const float* __restrict__ bias_p,
    float* __restrict__ out) {
    __shared__ __hip_bfloat16 lds_a[128 * 32];
    __shared__ __hip_bfloat16 lds_b[128 * 32];
    const int tid   = threadIdx.x;
    const int bn    = blockIdx.x & 15;
    const int bm    = blockIdx.x >> 4;
    const int w     = tid >> 6;
    const int lane  = tid & 63;
    const int col16 = lane & 15;
    const int quad  = lane >> 4;
    f32x4 acc[2][8];
#pragma unroll
    for (int mi = 0; mi < 2; ++mi)
#pragma unroll
        for (int ni = 0; ni < 8; ++ni)
            acc[mi][ni] = (f32x4){0.f, 0.f, 0.f, 0.f};
    const __hip_bfloat16* wt_base = Wt + (size_t)(bn * 128) * K_DIM;
    const int chunk0 = w * 2;
    const int e0     = chunk0 * 512 + lane * 8;
    const int bn_loc0 = e0 >> 5, bk_off0 = e0 & 31;
    const int e1     = (chunk0 + 1) * 512 + lane * 8;
    const int bn_loc1 = e1 >> 5, bk_off1 = e1 & 31;
    for (int kt = 0; kt < 32; ++kt) {
        const int kb = kt * 32;
        const float* aptr;
        int koff;
        if (kb < IN_DIM) { aptr = x; koff = kb; }
        else             { aptr = h; koff = kb - IN_DIM; }
        async_load16(wt_base + (size_t)bn_loc0 * K_DIM + kb + bk_off0,
                     (void*)(lds_b + chunk0 * 512));
        async_load16(wt_base + (size_t)bn_loc1 * K_DIM + kb + bk_off1,
                     (void*)(lds_b + (chunk0 + 1) * 512));
        float4 av[4];
#pragma unroll
        for (int j = 0; j < 4; ++j) {
            int cch = j * 256 + tid;
            int row = cch >> 3;
            int kq  = (cch & 7) * 4;
            av[j] = *(const float4*)(aptr + (size_t)(bm * 128 + row) * IN_DIM
                                     + koff + kq);
        }
#pragma unroll
        for (int j = 0; j < 4; ++j) {
            int cch = j * 256 + tid;
            int row = cch >> 3;
            int kq  = (cch & 7) * 4;
            short4v sv;
            sv.x = bf16bits(av[j].x);
            sv.y = bf16bits(av[j].y);
            sv.z = bf16bits(av[j].z);
            sv.w = bf16bits(av[j].w);
            *(short4v*)&lds_a[row * 32 + kq] = sv;
        }
        __syncthreads();
        short8 afr[2], bfr[8];
#pragma unroll
        for (int mi = 0; mi < 2; ++mi)
            afr[mi] = *(const short8*)&lds_a[(w * 32 + mi * 16 + col16) * 32 + quad * 8];
#pragma unroll
        for (int ni = 0; ni < 8; ++ni)
            bfr[ni] = *(const short8*)&lds_b[(ni * 16 + col16) * 32 + quad * 8];
#pragma unroll
        for (int mi = 0; mi < 2; ++mi)
#pragma unroll
            for (int ni = 0; ni < 8; ++ni)
                acc[mi][ni] = __builtin_amdgcn_mfma_f32_16x16x32_bf16(
                    afr[mi], bfr[ni], acc[mi][ni], 0, 0, 0);
        __syncthreads();
    }
    float bias_v[4][2];
#pragma unroll
    for (int g = 0; g < 4; ++g)
#pragma unroll
        for (int h2 = 0; h2 < 2; ++h2)
            bias_v[g][h2] = bias_p[bn * 128 + g * 32 + h2 * 16 + col16];
#pragma unroll
    for (int mi = 0; mi < 2; ++mi) {
#pragma unroll
        for (int reg = 0; reg < 4; ++reg) {
            const int m_g = bm * 128 + w * 32 + mi * 16 + quad * 4 + reg;
#pragma unroll
            for (int h2 = 0; h2 < 2; ++h2) {
                const int hc_g = bn * 32 + h2 * 16 + col16;
                float gi = acc[mi][0 + h2][reg] + bias_v[0][h2];
                float gf = acc[mi][2 + h2][reg] + bias_v[1][h2];
                float gg = acc[mi][4 + h2][reg] + bias_v[2][h2];
                float go = acc[mi][6 + h2][reg] + bias_v[3][h2];
                float iv = sigmoidf_(gi);
                float fv = sigmoidf_(gf);
                float gv = tanhf_(gg);
                float ov = sigmoidf_(go);
                float co = c_in[(size_t)m_g * H_DIM + hc_g];
                float cn = fv * co + iv * gv;
                float hn = ov * tanhf_(cn);
                out[(size_t)m_g * H_DIM + hc_g]      = hn;
                out[BH + (size_t)m_g * H_DIM + hc_g] = cn;
            }
        }
    }
}

extern "C" void kernel_launch(void* const* d_in, const int* in_sizes, int n_in,
                              void* d_out, int out_size, void* d_ws, size_t ws_size,
                              hipStream_t stream) {
    const float* x  = (const float*)d_in[0];
    const float* h  = (const float*)d_in[1];
    const float* c  = (const float*)d_in[2];
    const float* Wx = (const float*)d_in[3];
    const float* Wh = (const float*)d_in[4];
    const float* bx = (const float*)d_in[5];
    const float* bh = (const float*)d_in[6];

    const size_t wtBytes  = (size_t)N4H * K_DIM * 2;    // 4 MB
    const size_t axhBytes = (size_t)B_DIM * K_DIM * 2;  // 32 MB
    const size_t need     = wtBytes + axhBytes + (size_t)N4H * 4;

    if (ws_size >= need) {
        __hip_bfloat16* Wt  = (__hip_bfloat16*)d_ws;
        __hip_bfloat16* Axh = (__hip_bfloat16*)((char*)d_ws + wtBytes);
        float* bias_p = (float*)((char*)d_ws + wtBytes + axhBytes);
        prep_all<<<6144, 256, 0, stream>>>(Wx, Wh, bx, bh, x, h, Wt, Axh, bias_p);
        lstm_gemm256<<<512, 512, 0, stream>>>(c, Axh, Wt, bias_p, (float*)d_out);
    } else {
        __hip_bfloat16* Wt = (__hip_bfloat16*)d_ws;
        float* bias_p = (float*)((char*)d_ws + wtBytes);
        prep_weights_fb<<<2048, 256, 0, stream>>>(Wx, Wh, bx, bh, Wt, bias_p);
        lstm_gemm_fb<<<2048, 256, 0, stream>>>(x, h, c, Wt, bias_p, (float*)d_out);
    }
}